// Round 2
// baseline (599.135 us; speedup 1.0000x reference)
//
#include <hip/hip_runtime.h>
#include <math.h>

// CIF kernel. Key algebra: tokens[b,n,:] = (sum_t w[b,t,n] * h[b,t,:]) @ Wv + cif_mass[b,n]*bv
// so we never materialize v = h@Wv (34 GFLOP) nor dense w (26 TFLOP einsum).
// w is band-sparse: c = cumsum(alpha) is monotone -> each bin n covers a contiguous
// frame range found by binary search on c.
//
// R1: alpha_net/token_gemm moved to 512 threads/block (2 blocks/CU at 66KB LDS
// -> 4 waves/SIMD instead of 2; R0 showed VALUBusy 56% / Occupancy 22% = latency-
// bound on W1 L2 streams). scan_kernel now shfl-based (2 barriers/chunk vs ~20).
// cif_gather uses float4 + even/odd frame split for 2x memory parallelism.

#define T_LEN 4096
#define D_DIM 512
#define HID   128
#define N_MAX 400
#define B_SZ  16
#define EPSF  1e-8f

// 2 rows x 4 cols accumulate, one k-slice
#define FMA8(W, X0, X1) do { \
  acc[0][0] += (X0)*(W).x; acc[0][1] += (X0)*(W).y; acc[0][2] += (X0)*(W).z; acc[0][3] += (X0)*(W).w; \
  acc[1][0] += (X1)*(W).x; acc[1][1] += (X1)*(W).y; acc[1][2] += (X1)*(W).z; acc[1][3] += (X1)*(W).w; \
} while (0)

// ---------------------------------------------------------------------------
// K1: raw_alpha = softplus(silu(LN(h) @ W1 + b1) @ W2 + b2)   [B*T rows]
// 32 rows per block, 512 threads. LN'd rows staged in LDS (stride 516).
// GEMM: thread = (rg 0..15 -> 2 rows) x (jl 0..31 -> 4 hidden cols), k-step 4.
// ---------------------------------------------------------------------------
__global__ __launch_bounds__(512) void alpha_net_kernel(
    const float* __restrict__ h,
    const float* __restrict__ ln_g, const float* __restrict__ ln_b,
    const float* __restrict__ W1,   const float* __restrict__ b1,
    const float* __restrict__ W2,   const float* __restrict__ b2,
    float* __restrict__ raw_alpha)
{
    __shared__ float xn[32][516];
    const int tid  = threadIdx.x;
    const int row0 = blockIdx.x * 32;

    // ---- load 32 rows (32*512 f32) as float4, coalesced ----
    const float4* hsrc = (const float4*)(h + (size_t)row0 * D_DIM);
    #pragma unroll
    for (int i = 0; i < 8; ++i) {
        int idx = tid + i * 512;                 // 0..4095
        float4 v = hsrc[idx];
        *(float4*)&xn[idx >> 7][(idx & 127) << 2] = v;
    }
    __syncthreads();

    // ---- LayerNorm per row: 8 waves x 4 rows, contiguous float4 per lane ----
    const int wave = tid >> 6;
    const int lane = tid & 63;
    const int c1 = lane * 4;
    const int c2 = 256 + lane * 4;
    #pragma unroll
    for (int rr = 0; rr < 4; ++rr) {
        int r = wave * 4 + rr;
        float4 a  = *(const float4*)&xn[r][c1];
        float4 bq = *(const float4*)&xn[r][c2];
        float s  = a.x + a.y + a.z + a.w + bq.x + bq.y + bq.z + bq.w;
        float sq = a.x*a.x + a.y*a.y + a.z*a.z + a.w*a.w
                 + bq.x*bq.x + bq.y*bq.y + bq.z*bq.z + bq.w*bq.w;
        #pragma unroll
        for (int off = 32; off >= 1; off >>= 1) {
            s  += __shfl_xor(s,  off);
            sq += __shfl_xor(sq, off);
        }
        float mu  = s * (1.0f / 512.0f);
        float var = sq * (1.0f / 512.0f) - mu * mu;
        float inv = rsqrtf(var + 1e-5f);
        float4 g1 = *(const float4*)&ln_g[c1];
        float4 g2 = *(const float4*)&ln_g[c2];
        float4 o1 = *(const float4*)&ln_b[c1];
        float4 o2 = *(const float4*)&ln_b[c2];
        a.x  = (a.x  - mu) * inv * g1.x + o1.x;
        a.y  = (a.y  - mu) * inv * g1.y + o1.y;
        a.z  = (a.z  - mu) * inv * g1.z + o1.z;
        a.w  = (a.w  - mu) * inv * g1.w + o1.w;
        bq.x = (bq.x - mu) * inv * g2.x + o2.x;
        bq.y = (bq.y - mu) * inv * g2.y + o2.y;
        bq.z = (bq.z - mu) * inv * g2.z + o2.z;
        bq.w = (bq.w - mu) * inv * g2.w + o2.w;
        *(float4*)&xn[r][c1] = a;
        *(float4*)&xn[r][c2] = bq;
    }
    __syncthreads();

    // ---- xn @ W1: 2 rows x 4 cols per thread, k in steps of 4 ----
    const int jl = tid & 31;
    const int rg = tid >> 5;                     // 0..15
    const int j4 = jl * 4;
    const int rbase = rg * 2;
    float acc[2][4] = {};
    for (int k4 = 0; k4 < 128; ++k4) {
        int k = k4 << 2;
        float4 wA = *(const float4*)&W1[(k + 0) * HID + j4];
        float4 wB = *(const float4*)&W1[(k + 1) * HID + j4];
        float4 wC = *(const float4*)&W1[(k + 2) * HID + j4];
        float4 wD = *(const float4*)&W1[(k + 3) * HID + j4];
        float4 x0 = *(const float4*)&xn[rbase + 0][k];
        float4 x1 = *(const float4*)&xn[rbase + 1][k];
        FMA8(wA, x0.x, x1.x);
        FMA8(wB, x0.y, x1.y);
        FMA8(wC, x0.z, x1.z);
        FMA8(wD, x0.w, x1.w);
    }

    // ---- +b1, SiLU, dot W2 over this thread's 4 cols, reduce across 32 lanes ----
    float4 b1q = *(const float4*)&b1[j4];
    float4 w2q = *(const float4*)&W2[j4];
    float b2s  = b2[0];
    float srow[2];
    #pragma unroll
    for (int r = 0; r < 2; ++r) {
        float z0 = acc[r][0] + b1q.x;
        float z1 = acc[r][1] + b1q.y;
        float z2 = acc[r][2] + b1q.z;
        float z3 = acc[r][3] + b1q.w;
        float s = z0 / (1.f + expf(-z0)) * w2q.x
                + z1 / (1.f + expf(-z1)) * w2q.y
                + z2 / (1.f + expf(-z2)) * w2q.z
                + z3 / (1.f + expf(-z3)) * w2q.w;
        s += __shfl_xor(s, 16);
        s += __shfl_xor(s, 8);
        s += __shfl_xor(s, 4);
        s += __shfl_xor(s, 2);
        s += __shfl_xor(s, 1);
        srow[r] = s;
    }
    if (jl == 0) {
        #pragma unroll
        for (int r = 0; r < 2; ++r) {
            float z  = srow[r] + b2s;
            // jax softplus = logaddexp(z, 0) = max(z,0) + log1p(exp(-|z|))
            float sp = fmaxf(z, 0.f) + log1pf(expf(-fabsf(z)));
            raw_alpha[row0 + rbase + r] = sp;
        }
    }
}

// ---------------------------------------------------------------------------
// K2: per-batch masked sum -> scale -> alpha -> inclusive cumsum c (to ws).
// One block per batch, 1024 threads (16 waves), shfl-based scan.
// ---------------------------------------------------------------------------
__global__ __launch_bounds__(1024) void scan_kernel(
    const float* __restrict__ raw, const int* __restrict__ tgt,
    const int* __restrict__ ilen, float* __restrict__ alpha_out,
    float* __restrict__ c_out)
{
    __shared__ float wsum_lds[16];
    __shared__ float wscan_lds[16];
    __shared__ float sh_scale, sh_uu, sh_unif;
    const int b    = blockIdx.x;
    const int tid  = threadIdx.x;
    const int wid  = tid >> 6;
    const int lane = tid & 63;
    const int L    = min(ilen[b], T_LEN);
    const float Nf = (float)tgt[b];
    const float* rb = raw + b * T_LEN;

    // masked sum over valid frames
    float local = 0.f;
    #pragma unroll
    for (int i = 0; i < 4; ++i) {
        int t = tid + (i << 10);
        if (t < L) local += rb[t];
    }
    #pragma unroll
    for (int off = 32; off >= 1; off >>= 1) local += __shfl_xor(local, off);
    if (lane == 0) wsum_lds[wid] = local;
    __syncthreads();
    if (tid == 0) {
        float sums = 0.f;
        #pragma unroll
        for (int i = 0; i < 16; ++i) sums += wsum_lds[i];
        sh_scale = Nf / (sums + EPSF);
        sh_uu    = (sums < 10.f * EPSF) ? 1.f : 0.f;
        sh_unif  = Nf / fmaxf((float)L, 1.f);
    }
    __syncthreads();
    const float scale = sh_scale, uu = sh_uu, unif = sh_unif;

    float carry = 0.f;
    for (int ch = 0; ch < 4; ++ch) {
        int t = (ch << 10) + tid;
        float m = (t < L) ? 1.f : 0.f;
        float a = (rb[t] * m * scale) * (1.f - uu) + m * unif * uu;
        alpha_out[b * T_LEN + t] = a;
        // intra-wave inclusive scan
        float v = a;
        #pragma unroll
        for (int off = 1; off < 64; off <<= 1) {
            float tv = __shfl_up(v, off);
            if (lane >= off) v += tv;
        }
        __syncthreads();              // wsum_lds safe to overwrite
        if (lane == 63) wsum_lds[wid] = v;
        __syncthreads();
        if (wid == 0 && lane < 16) {
            float s = wsum_lds[lane];
            #pragma unroll
            for (int off = 1; off < 16; off <<= 1) {
                float tv = __shfl_up(s, off);
                if (lane >= off) s += tv;
            }
            wscan_lds[lane] = s;
        }
        __syncthreads();
        float woff = (wid > 0) ? wscan_lds[wid - 1] : 0.f;
        c_out[b * T_LEN + t] = carry + woff + v;
        carry += wscan_lds[15];
    }
}

// ---------------------------------------------------------------------------
// K3: per (b, bin n): binary-search contiguous frame range, accumulate
// hw[b,n,:] = sum_t w*h[b,t,:], plus cif_mass / frame_durations / token_mask.
// float4 cols, even/odd frame split across thread halves (2 frames in flight).
// ---------------------------------------------------------------------------
__global__ __launch_bounds__(256) void cif_gather_kernel(
    const float* __restrict__ h, const float* __restrict__ alpha,
    const float* __restrict__ c_arr,
    const int* __restrict__ tgt, const int* __restrict__ ilen,
    float* __restrict__ hw, float* __restrict__ fd_out,
    float* __restrict__ cm_out, float* __restrict__ tm_out)
{
    __shared__ float part[514];        // 512 col partials + wsum,fdsum
    const int n   = blockIdx.x;
    const int b   = blockIdx.y;
    const int tid = threadIdx.x;
    const int oidx = b * N_MAX + n;
    if (n >= tgt[b]) {
        if (tid == 0) { fd_out[oidx] = 0.f; cm_out[oidx] = 0.f; tm_out[oidx] = 0.f; }
        return;   // hw row left as (finite) poison; K4 masks it to zero
    }
    const int L = min(ilen[b], T_LEN);
    const float* cb = c_arr + b * T_LEN;
    const float* ab = alpha + b * T_LEN;
    const float nf  = (float)n;
    const float nf1 = nf + 1.0f;

    // first t with c[t] > n
    int lo = 0, hi = T_LEN;
    while (lo < hi) { int mid = (lo + hi) >> 1; if (cb[mid] > nf) hi = mid; else lo = mid + 1; }
    const int t0 = lo;
    // first t with c[t] >= n+1  (== last contributing frame, since c_prev[t]=c[t-1])
    lo = 0; hi = T_LEN;
    while (lo < hi) { int mid = (lo + hi) >> 1; if (cb[mid] >= nf1) hi = mid; else lo = mid + 1; }
    int t1 = min(lo, L - 1);

    const int par = tid >> 7;          // 0: even frames, 1: odd frames
    const int c4  = (tid & 127) << 2;  // float column base
    float4 acc = make_float4(0.f, 0.f, 0.f, 0.f);
    float wsum = 0.f, fdsum = 0.f;
    const float* hb = h + (size_t)(b * T_LEN) * D_DIM;
    for (int t = t0 + par; t <= t1; t += 2) {
        float a = ab[t], c = cb[t];
        float cp = c - a;                               // c_prev, same arithmetic as ref
        float w  = fmaxf(fminf(c, nf1) - fmaxf(cp, nf), 0.f);
        wsum  += w;
        fdsum += w / (a + EPSF);
        const float4 hv = *(const float4*)(hb + (size_t)t * D_DIM + c4);
        acc.x += w * hv.x;
        acc.y += w * hv.y;
        acc.z += w * hv.z;
        acc.w += w * hv.w;
    }
    if (par == 1) {
        *(float4*)&part[c4] = acc;
        if (tid == 128) { part[512] = wsum; part[513] = fdsum; }
    }
    __syncthreads();
    if (par == 0) {
        float4 p = *(const float4*)&part[c4];
        acc.x += p.x; acc.y += p.y; acc.z += p.z; acc.w += p.w;
        *(float4*)(hw + (size_t)oidx * D_DIM + c4) = acc;
        if (tid == 0) {
            fd_out[oidx] = fdsum + part[513];
            cm_out[oidx] = wsum + part[512];
            tm_out[oidx] = 1.f;
        }
    }
}

// ---------------------------------------------------------------------------
// K4: tokens = (hw @ Wv + cif_mass*bv) * token_mask.  M=6400, N=512, K=512.
// 32x128 tile per block, 512 threads, 2 rows x 4 cols micro-tile, A in LDS.
// ---------------------------------------------------------------------------
__global__ __launch_bounds__(512) void token_gemm_kernel(
    const float* __restrict__ hw, const float* __restrict__ Wv,
    const float* __restrict__ bv, const float* __restrict__ cm,
    const int* __restrict__ tgt, float* __restrict__ tokens)
{
    __shared__ float As[32][516];
    const int tid  = threadIdx.x;
    const int row0 = blockIdx.x * 32;
    const int colb = blockIdx.y * 128;

    const float4* src = (const float4*)(hw + (size_t)row0 * D_DIM);
    #pragma unroll
    for (int i = 0; i < 8; ++i) {
        int idx = tid + i * 512;
        float4 v = src[idx];
        *(float4*)&As[idx >> 7][(idx & 127) << 2] = v;
    }
    __syncthreads();

    const int jl = tid & 31;
    const int rg = tid >> 5;                   // 0..15
    const int col = colb + jl * 4;
    const int rbase = rg * 2;
    float acc[2][4] = {};
    for (int k4 = 0; k4 < 128; ++k4) {
        int k = k4 << 2;
        float4 wA = *(const float4*)&Wv[(size_t)(k + 0) * D_DIM + col];
        float4 wB = *(const float4*)&Wv[(size_t)(k + 1) * D_DIM + col];
        float4 wC = *(const float4*)&Wv[(size_t)(k + 2) * D_DIM + col];
        float4 wD = *(const float4*)&Wv[(size_t)(k + 3) * D_DIM + col];
        float4 x0 = *(const float4*)&As[rbase + 0][k];
        float4 x1 = *(const float4*)&As[rbase + 1][k];
        FMA8(wA, x0.x, x1.x);
        FMA8(wB, x0.y, x1.y);
        FMA8(wC, x0.z, x1.z);
        FMA8(wD, x0.w, x1.w);
    }

    float4 bq = *(const float4*)&bv[col];
    #pragma unroll
    for (int r = 0; r < 2; ++r) {
        int row = row0 + rbase + r;
        int bb  = row / N_MAX;
        int nn  = row - bb * N_MAX;
        float m  = (nn < tgt[bb]) ? 1.f : 0.f;
        float wm = cm[row];                     // already masked (0 for masked bins)
        float4 o;
        o.x = m * (acc[r][0] + wm * bq.x);
        o.y = m * (acc[r][1] + wm * bq.y);
        o.z = m * (acc[r][2] + wm * bq.z);
        o.w = m * (acc[r][3] + wm * bq.w);
        *(float4*)&tokens[(size_t)row * D_DIM + col] = o;
    }
}

// ---------------------------------------------------------------------------
extern "C" void kernel_launch(void* const* d_in, const int* in_sizes, int n_in,
                              void* d_out, int out_size, void* d_ws, size_t ws_size,
                              hipStream_t stream)
{
    (void)in_sizes; (void)n_in; (void)out_size; (void)ws_size;
    const float* h    = (const float*)d_in[0];
    const int*   tgt  = (const int*)  d_in[1];
    const int*   ilen = (const int*)  d_in[2];
    const float* lng  = (const float*)d_in[3];
    const float* lnb  = (const float*)d_in[4];
    const float* W1   = (const float*)d_in[5];
    const float* b1   = (const float*)d_in[6];
    const float* W2   = (const float*)d_in[7];
    const float* b2   = (const float*)d_in[8];
    const float* Wv   = (const float*)d_in[9];
    const float* bv   = (const float*)d_in[10];

    float* out    = (float*)d_out;
    float* tokens = out;                                        // [B, N_MAX, V]
    float* fd     = tokens + (size_t)B_SZ * N_MAX * D_DIM;      // [B, N_MAX]
    float* cm     = fd + B_SZ * N_MAX;                          // [B, N_MAX]
    float* tm     = cm + B_SZ * N_MAX;                          // [B, N_MAX]
    float* alpha  = tm + B_SZ * N_MAX;                          // [B, T]
    float* raw    = alpha + B_SZ * T_LEN;                       // [B, T]

    float* c_ws = (float*)d_ws;                                 // [B, T]
    float* hw   = c_ws + (size_t)B_SZ * T_LEN;                  // [B*N_MAX, D]

    alpha_net_kernel<<<(B_SZ * T_LEN) / 32, 512, 0, stream>>>(h, lng, lnb, W1, b1, W2, b2, raw);
    scan_kernel<<<B_SZ, 1024, 0, stream>>>(raw, tgt, ilen, alpha, c_ws);
    cif_gather_kernel<<<dim3(N_MAX, B_SZ), 256, 0, stream>>>(h, alpha, c_ws, tgt, ilen,
                                                             hw, fd, cm, tm);
    token_gemm_kernel<<<dim3((B_SZ * N_MAX) / 32, 4), 512, 0, stream>>>(hw, Wv, bv, cm, tgt, tokens);
}

// Round 3
// 559.424 us; speedup vs baseline: 1.0710x; 1.0710x over previous
//
#include <hip/hip_runtime.h>
#include <math.h>

// CIF kernel. Key algebra: tokens[b,n,:] = (sum_t w[b,t,n] * h[b,t,:]) @ Wv + cif_mass[b,n]*bv
// so we never materialize v = h@Wv (34 GFLOP) nor dense w (26 TFLOP einsum).
// w is band-sparse: c = cumsum(alpha) is monotone -> each bin n covers a contiguous
// frame range found by binary search on c.
//
// R2: R1's 512-thr variant regressed (L2 weight re-fetch doubled: VALUBusy 49%).
// Root cause both rounds: every row-group re-reads all of W from L2 (~2-4 GB).
// Fix: stage W tiles in LDS (BK=32, 16 KB) -> weights hit L2 once per block.
// LDS = 64 KB A-tile (unpadded; broadcast/2-way reads are conflict-free) +
// 16 KB W-tile = exactly 80 KB -> 2 blocks/CU. Scan split into 64-block
// chunk-sum + 64-block chunked scan for parallelism.

#define T_LEN 4096
#define D_DIM 512
#define HID   128
#define N_MAX 400
#define B_SZ  16
#define EPSF  1e-8f

#define FMA16(W, X0, X1, X2, X3) do { \
  acc[0][0] += (X0)*(W).x; acc[0][1] += (X0)*(W).y; acc[0][2] += (X0)*(W).z; acc[0][3] += (X0)*(W).w; \
  acc[1][0] += (X1)*(W).x; acc[1][1] += (X1)*(W).y; acc[1][2] += (X1)*(W).z; acc[1][3] += (X1)*(W).w; \
  acc[2][0] += (X2)*(W).x; acc[2][1] += (X2)*(W).y; acc[2][2] += (X2)*(W).z; acc[2][3] += (X2)*(W).w; \
  acc[3][0] += (X3)*(W).x; acc[3][1] += (X3)*(W).y; acc[3][2] += (X3)*(W).z; acc[3][3] += (X3)*(W).w; \
} while (0)

// ---------------------------------------------------------------------------
// K1: raw_alpha = softplus(silu(LN(h) @ W1 + b1) @ W2 + b2)   [B*T rows]
// 32 rows/block, 256 threads. LN'd rows in LDS; W1 staged in LDS per BK=32.
// GEMM: thread = (rg 0..7 -> 4 rows) x (jl 0..31 -> 4 hidden cols), k-step 4.
// ---------------------------------------------------------------------------
__global__ __launch_bounds__(256) void alpha_net_kernel(
    const float* __restrict__ h,
    const float* __restrict__ ln_g, const float* __restrict__ ln_b,
    const float* __restrict__ W1,   const float* __restrict__ b1,
    const float* __restrict__ W2,   const float* __restrict__ b2,
    float* __restrict__ raw_alpha)
{
    __shared__ float xn[32][512];    // 64 KB
    __shared__ float Wt[32][128];    // 16 KB  (total exactly 80 KB -> 2 blocks/CU)
    const int tid  = threadIdx.x;
    const int row0 = blockIdx.x * 32;

    // ---- load 32 rows (32*512 f32) as float4, coalesced ----
    const float4* hsrc = (const float4*)(h + (size_t)row0 * D_DIM);
    #pragma unroll
    for (int i = 0; i < 16; ++i) {
        int idx = tid + i * 256;                 // 0..4095
        float4 v = hsrc[idx];
        *(float4*)&xn[idx >> 7][(idx & 127) << 2] = v;
    }
    __syncthreads();

    // ---- LayerNorm in place: 4 waves x 8 rows, contiguous float4 per lane ----
    const int wave = tid >> 6;
    const int lane = tid & 63;
    const int c1 = lane * 4;
    const int c2 = 256 + lane * 4;
    #pragma unroll
    for (int rr = 0; rr < 8; ++rr) {
        int r = wave * 8 + rr;
        float4 a  = *(const float4*)&xn[r][c1];
        float4 bq = *(const float4*)&xn[r][c2];
        float s  = a.x + a.y + a.z + a.w + bq.x + bq.y + bq.z + bq.w;
        float sq = a.x*a.x + a.y*a.y + a.z*a.z + a.w*a.w
                 + bq.x*bq.x + bq.y*bq.y + bq.z*bq.z + bq.w*bq.w;
        #pragma unroll
        for (int off = 32; off >= 1; off >>= 1) {
            s  += __shfl_xor(s,  off);
            sq += __shfl_xor(sq, off);
        }
        float mu  = s * (1.0f / 512.0f);
        float var = sq * (1.0f / 512.0f) - mu * mu;
        float inv = rsqrtf(var + 1e-5f);
        float4 g1 = *(const float4*)&ln_g[c1];
        float4 g2 = *(const float4*)&ln_g[c2];
        float4 o1 = *(const float4*)&ln_b[c1];
        float4 o2 = *(const float4*)&ln_b[c2];
        a.x  = (a.x  - mu) * inv * g1.x + o1.x;
        a.y  = (a.y  - mu) * inv * g1.y + o1.y;
        a.z  = (a.z  - mu) * inv * g1.z + o1.z;
        a.w  = (a.w  - mu) * inv * g1.w + o1.w;
        bq.x = (bq.x - mu) * inv * g2.x + o2.x;
        bq.y = (bq.y - mu) * inv * g2.y + o2.y;
        bq.z = (bq.z - mu) * inv * g2.z + o2.z;
        bq.w = (bq.w - mu) * inv * g2.w + o2.w;
        *(float4*)&xn[r][c1] = a;
        *(float4*)&xn[r][c2] = bq;
    }
    __syncthreads();

    // ---- xn @ W1 with W1 staged in LDS: 4 rows x 4 cols per thread ----
    const int jl = tid & 31;
    const int rg = tid >> 5;
    const int j4 = jl * 4;
    const int rbase = rg * 4;
    float acc[4][4] = {};
    for (int kc = 0; kc < D_DIM; kc += 32) {
        #pragma unroll
        for (int i = 0; i < 4; ++i) {
            int idx = tid + i * 256;             // 0..1023 float4
            int kk = idx >> 5;
            int cc = (idx & 31) << 2;
            *(float4*)&Wt[kk][cc] = *(const float4*)&W1[(size_t)(kc + kk) * HID + cc];
        }
        __syncthreads();
        #pragma unroll
        for (int k4 = 0; k4 < 8; ++k4) {
            int k = k4 << 2;
            float4 wA = *(const float4*)&Wt[k + 0][j4];
            float4 wB = *(const float4*)&Wt[k + 1][j4];
            float4 wC = *(const float4*)&Wt[k + 2][j4];
            float4 wD = *(const float4*)&Wt[k + 3][j4];
            float4 x0 = *(const float4*)&xn[rbase + 0][kc + k];
            float4 x1 = *(const float4*)&xn[rbase + 1][kc + k];
            float4 x2 = *(const float4*)&xn[rbase + 2][kc + k];
            float4 x3 = *(const float4*)&xn[rbase + 3][kc + k];
            FMA16(wA, x0.x, x1.x, x2.x, x3.x);
            FMA16(wB, x0.y, x1.y, x2.y, x3.y);
            FMA16(wC, x0.z, x1.z, x2.z, x3.z);
            FMA16(wD, x0.w, x1.w, x2.w, x3.w);
        }
        __syncthreads();
    }

    // ---- +b1, SiLU, dot W2 over this thread's 4 cols, reduce across 32 lanes ----
    float4 b1q = *(const float4*)&b1[j4];
    float4 w2q = *(const float4*)&W2[j4];
    float b2s  = b2[0];
    float srow[4];
    #pragma unroll
    for (int r = 0; r < 4; ++r) {
        float z0 = acc[r][0] + b1q.x;
        float z1 = acc[r][1] + b1q.y;
        float z2 = acc[r][2] + b1q.z;
        float z3 = acc[r][3] + b1q.w;
        float s = z0 / (1.f + expf(-z0)) * w2q.x
                + z1 / (1.f + expf(-z1)) * w2q.y
                + z2 / (1.f + expf(-z2)) * w2q.z
                + z3 / (1.f + expf(-z3)) * w2q.w;
        s += __shfl_xor(s, 16);
        s += __shfl_xor(s, 8);
        s += __shfl_xor(s, 4);
        s += __shfl_xor(s, 2);
        s += __shfl_xor(s, 1);
        srow[r] = s;
    }
    if (jl == 0) {
        #pragma unroll
        for (int r = 0; r < 4; ++r) {
            float z  = srow[r] + b2s;
            // jax softplus = logaddexp(z, 0) = max(z,0) + log1p(exp(-|z|))
            float sp = fmaxf(z, 0.f) + log1pf(expf(-fabsf(z)));
            raw_alpha[row0 + rbase + r] = sp;
        }
    }
}

// ---------------------------------------------------------------------------
// K2a: masked chunk sums S[b][ch] over raw alpha. Grid (4, B), 256 thr.
// ---------------------------------------------------------------------------
__global__ __launch_bounds__(256) void chunk_sum_kernel(
    const float* __restrict__ raw, const int* __restrict__ ilen,
    float* __restrict__ S)
{
    __shared__ float wred[4];
    const int ch = blockIdx.x, b = blockIdx.y;
    const int tid = threadIdx.x;
    const int L = min(ilen[b], T_LEN);
    const int base = ch << 10;
    float local = 0.f;
    #pragma unroll
    for (int i = 0; i < 4; ++i) {
        int t = base + tid + (i << 8);
        if (t < L) local += raw[b * T_LEN + t];
    }
    #pragma unroll
    for (int off = 32; off >= 1; off >>= 1) local += __shfl_xor(local, off);
    if ((tid & 63) == 0) wred[tid >> 6] = local;
    __syncthreads();
    if (tid == 0) S[b * 4 + ch] = wred[0] + wred[1] + wred[2] + wred[3];
}

// ---------------------------------------------------------------------------
// K2b: per (b, chunk): scale raw -> alpha, inclusive scan -> c. Grid (4, B),
// 1024 thr (16 waves). Carry derived from chunk sums (algebraically exact).
// ---------------------------------------------------------------------------
__global__ __launch_bounds__(1024) void scan_chunk_kernel(
    const float* __restrict__ raw, const float* __restrict__ S,
    const int* __restrict__ tgt, const int* __restrict__ ilen,
    float* __restrict__ alpha_out, float* __restrict__ c_out)
{
    __shared__ float wsum_lds[16];
    __shared__ float wscan_lds[16];
    const int ch = blockIdx.x, b = blockIdx.y;
    const int tid  = threadIdx.x;
    const int wid  = tid >> 6;
    const int lane = tid & 63;
    const int L    = min(ilen[b], T_LEN);
    const float Nf = (float)tgt[b];

    float s0 = S[b * 4 + 0], s1 = S[b * 4 + 1], s2 = S[b * 4 + 2], s3 = S[b * 4 + 3];
    float sums  = s0 + s1 + s2 + s3;
    float scale = Nf / (sums + EPSF);
    float uu    = (sums < 10.f * EPSF) ? 1.f : 0.f;
    float unif  = Nf / fmaxf((float)L, 1.f);
    float prefix = (ch > 0 ? s0 : 0.f) + (ch > 1 ? s1 : 0.f) + (ch > 2 ? s2 : 0.f);
    float carry  = (1.f - uu) * scale * prefix
                 + uu * unif * (float)min(L, ch << 10);

    int t = (ch << 10) + tid;
    float m = (t < L) ? 1.f : 0.f;
    float a = (raw[b * T_LEN + t] * m * scale) * (1.f - uu) + m * unif * uu;
    alpha_out[b * T_LEN + t] = a;

    float v = a;
    #pragma unroll
    for (int off = 1; off < 64; off <<= 1) {
        float tv = __shfl_up(v, off);
        if (lane >= off) v += tv;
    }
    if (lane == 63) wsum_lds[wid] = v;
    __syncthreads();
    if (wid == 0 && lane < 16) {
        float s = wsum_lds[lane];
        #pragma unroll
        for (int off = 1; off < 16; off <<= 1) {
            float tv = __shfl_up(s, off);
            if (lane >= off) s += tv;
        }
        wscan_lds[lane] = s;
    }
    __syncthreads();
    float woff = (wid > 0) ? wscan_lds[wid - 1] : 0.f;
    c_out[b * T_LEN + t] = carry + woff + v;
}

// ---------------------------------------------------------------------------
// K3: per (b, bin n): binary-search contiguous frame range, accumulate
// hw[b,n,:] = sum_t w*h[b,t,:], plus cif_mass / frame_durations / token_mask.
// float4 cols, even/odd frame split across thread halves (2 frames in flight).
// ---------------------------------------------------------------------------
__global__ __launch_bounds__(256) void cif_gather_kernel(
    const float* __restrict__ h, const float* __restrict__ alpha,
    const float* __restrict__ c_arr,
    const int* __restrict__ tgt, const int* __restrict__ ilen,
    float* __restrict__ hw, float* __restrict__ fd_out,
    float* __restrict__ cm_out, float* __restrict__ tm_out)
{
    __shared__ float part[514];        // 512 col partials + wsum,fdsum
    const int n   = blockIdx.x;
    const int b   = blockIdx.y;
    const int tid = threadIdx.x;
    const int oidx = b * N_MAX + n;
    if (n >= tgt[b]) {
        if (tid == 0) { fd_out[oidx] = 0.f; cm_out[oidx] = 0.f; tm_out[oidx] = 0.f; }
        return;   // hw row left as (finite) poison; K4 masks it to zero
    }
    const int L = min(ilen[b], T_LEN);
    const float* cb = c_arr + b * T_LEN;
    const float* ab = alpha + b * T_LEN;
    const float nf  = (float)n;
    const float nf1 = nf + 1.0f;

    // first t with c[t] > n
    int lo = 0, hi = T_LEN;
    while (lo < hi) { int mid = (lo + hi) >> 1; if (cb[mid] > nf) hi = mid; else lo = mid + 1; }
    const int t0 = lo;
    // first t with c[t] >= n+1  (== last contributing frame, since c_prev[t]=c[t-1])
    lo = 0; hi = T_LEN;
    while (lo < hi) { int mid = (lo + hi) >> 1; if (cb[mid] >= nf1) hi = mid; else lo = mid + 1; }
    int t1 = min(lo, L - 1);

    const int par = tid >> 7;          // 0: even frames, 1: odd frames
    const int c4  = (tid & 127) << 2;  // float column base
    float4 acc = make_float4(0.f, 0.f, 0.f, 0.f);
    float wsum = 0.f, fdsum = 0.f;
    const float* hb = h + (size_t)(b * T_LEN) * D_DIM;
    for (int t = t0 + par; t <= t1; t += 2) {
        float a = ab[t], c = cb[t];
        float cp = c - a;                               // c_prev, same arithmetic as ref
        float w  = fmaxf(fminf(c, nf1) - fmaxf(cp, nf), 0.f);
        wsum  += w;
        fdsum += w / (a + EPSF);
        const float4 hv = *(const float4*)(hb + (size_t)t * D_DIM + c4);
        acc.x += w * hv.x;
        acc.y += w * hv.y;
        acc.z += w * hv.z;
        acc.w += w * hv.w;
    }
    if (par == 1) {
        *(float4*)&part[c4] = acc;
        if (tid == 128) { part[512] = wsum; part[513] = fdsum; }
    }
    __syncthreads();
    if (par == 0) {
        float4 p = *(const float4*)&part[c4];
        acc.x += p.x; acc.y += p.y; acc.z += p.z; acc.w += p.w;
        *(float4*)(hw + (size_t)oidx * D_DIM + c4) = acc;
        if (tid == 0) {
            fd_out[oidx] = fdsum + part[513];
            cm_out[oidx] = wsum + part[512];
            tm_out[oidx] = 1.f;
        }
    }
}

// ---------------------------------------------------------------------------
// K4: tokens = (hw @ Wv + cif_mass*bv) * token_mask.  M=6400, N=512, K=512.
// 32x128 tile per block, 256 threads, Wv staged in LDS per BK=32.
// ---------------------------------------------------------------------------
__global__ __launch_bounds__(256) void token_gemm_kernel(
    const float* __restrict__ hw, const float* __restrict__ Wv,
    const float* __restrict__ bv, const float* __restrict__ cm,
    const int* __restrict__ tgt, float* __restrict__ tokens)
{
    __shared__ float As[32][512];    // 64 KB
    __shared__ float Wt[32][128];    // 16 KB
    const int tid  = threadIdx.x;
    const int row0 = blockIdx.x * 32;
    const int colb = blockIdx.y * 128;

    const float4* src = (const float4*)(hw + (size_t)row0 * D_DIM);
    #pragma unroll
    for (int i = 0; i < 16; ++i) {
        int idx = tid + i * 256;
        float4 v = src[idx];
        *(float4*)&As[idx >> 7][(idx & 127) << 2] = v;
    }
    __syncthreads();

    const int jl = tid & 31;
    const int rg = tid >> 5;
    const int col = colb + jl * 4;
    const int rbase = rg * 4;
    float acc[4][4] = {};
    for (int kc = 0; kc < D_DIM; kc += 32) {
        #pragma unroll
        for (int i = 0; i < 4; ++i) {
            int idx = tid + i * 256;             // 0..1023 float4
            int kk = idx >> 5;
            int cc = (idx & 31) << 2;
            *(float4*)&Wt[kk][cc] = *(const float4*)&Wv[(size_t)(kc + kk) * D_DIM + colb + cc];
        }
        __syncthreads();
        #pragma unroll
        for (int k4 = 0; k4 < 8; ++k4) {
            int k = k4 << 2;
            float4 wA = *(const float4*)&Wt[k + 0][jl * 4];
            float4 wB = *(const float4*)&Wt[k + 1][jl * 4];
            float4 wC = *(const float4*)&Wt[k + 2][jl * 4];
            float4 wD = *(const float4*)&Wt[k + 3][jl * 4];
            float4 x0 = *(const float4*)&As[rbase + 0][kc + k];
            float4 x1 = *(const float4*)&As[rbase + 1][kc + k];
            float4 x2 = *(const float4*)&As[rbase + 2][kc + k];
            float4 x3 = *(const float4*)&As[rbase + 3][kc + k];
            FMA16(wA, x0.x, x1.x, x2.x, x3.x);
            FMA16(wB, x0.y, x1.y, x2.y, x3.y);
            FMA16(wC, x0.z, x1.z, x2.z, x3.z);
            FMA16(wD, x0.w, x1.w, x2.w, x3.w);
        }
        __syncthreads();
    }

    float4 bq = *(const float4*)&bv[col];
    #pragma unroll
    for (int r = 0; r < 4; ++r) {
        int row = row0 + rbase + r;
        int bb  = row / N_MAX;
        int nn  = row - bb * N_MAX;
        float m  = (nn < tgt[bb]) ? 1.f : 0.f;
        float wm = cm[row];                     // already masked (0 for masked bins)
        float4 o;
        o.x = m * (acc[r][0] + wm * bq.x);
        o.y = m * (acc[r][1] + wm * bq.y);
        o.z = m * (acc[r][2] + wm * bq.z);
        o.w = m * (acc[r][3] + wm * bq.w);
        *(float4*)&tokens[(size_t)row * D_DIM + col] = o;
    }
}

// ---------------------------------------------------------------------------
extern "C" void kernel_launch(void* const* d_in, const int* in_sizes, int n_in,
                              void* d_out, int out_size, void* d_ws, size_t ws_size,
                              hipStream_t stream)
{
    (void)in_sizes; (void)n_in; (void)out_size; (void)ws_size;
    const float* h    = (const float*)d_in[0];
    const int*   tgt  = (const int*)  d_in[1];
    const int*   ilen = (const int*)  d_in[2];
    const float* lng  = (const float*)d_in[3];
    const float* lnb  = (const float*)d_in[4];
    const float* W1   = (const float*)d_in[5];
    const float* b1   = (const float*)d_in[6];
    const float* W2   = (const float*)d_in[7];
    const float* b2   = (const float*)d_in[8];
    const float* Wv   = (const float*)d_in[9];
    const float* bv   = (const float*)d_in[10];

    float* out    = (float*)d_out;
    float* tokens = out;                                        // [B, N_MAX, V]
    float* fd     = tokens + (size_t)B_SZ * N_MAX * D_DIM;      // [B, N_MAX]
    float* cm     = fd + B_SZ * N_MAX;                          // [B, N_MAX]
    float* tm     = cm + B_SZ * N_MAX;                          // [B, N_MAX]
    float* alpha  = tm + B_SZ * N_MAX;                          // [B, T]
    float* raw    = alpha + B_SZ * T_LEN;                       // [B, T]

    float* c_ws = (float*)d_ws;                                 // [B, T]
    float* hw   = c_ws + (size_t)B_SZ * T_LEN;                  // [B*N_MAX, D]
    float* S    = hw + (size_t)B_SZ * N_MAX * D_DIM;            // [B, 4] chunk sums

    alpha_net_kernel<<<(B_SZ * T_LEN) / 32, 256, 0, stream>>>(h, lng, lnb, W1, b1, W2, b2, raw);
    chunk_sum_kernel<<<dim3(4, B_SZ), 256, 0, stream>>>(raw, ilen, S);
    scan_chunk_kernel<<<dim3(4, B_SZ), 1024, 0, stream>>>(raw, S, tgt, ilen, alpha, c_ws);
    cif_gather_kernel<<<dim3(N_MAX, B_SZ), 256, 0, stream>>>(h, alpha, c_ws, tgt, ilen,
                                                             hw, fd, cm, tm);
    token_gemm_kernel<<<dim3((B_SZ * N_MAX) / 32, 4), 256, 0, stream>>>(hw, Wv, bv, cm, tgt, tokens);
}

// Round 6
// 443.977 us; speedup vs baseline: 1.3495x; 1.2600x over previous
//
#include <hip/hip_runtime.h>
#include <math.h>

// CIF kernel. Key algebra: tokens[b,n,:] = (sum_t w[b,t,n] * h[b,t,:]) @ Wv + cif_mass[b,n]*bv
// so we never materialize v = h@Wv (34 GFLOP) nor dense w (26 TFLOP einsum).
// w is band-sparse: c = cumsum(alpha) is monotone -> each bin n covers a contiguous
// frame range found by binary search on c.
//
// R4/R5 both hit GPUAcquisitionTimeout; this is the same kernel resubmitted.
// Both GEMMs (alpha_net, token_gemm) keep R0's 32-row/4x4 micro-tile
// (VALU-bound inner loop) but stage W in LDS with BK=16 (8 KB) -> 72 KB total
// -> 2 blocks/CU (R2's 80 KB gave only 1). Next W-chunk is prefetched into
// registers during compute (issue-early/write-late) so L2 latency hides.
// History: R0 219us alpha (W from L2 every wave, ~2.1 GB L2); R1 512-thr
// regressed (+96us, W traffic doubled); R2 W-in-LDS at 80KB regressed
// (1 block/CU, occupancy 11.5%).

#define T_LEN 4096
#define D_DIM 512
#define HID   128
#define N_MAX 400
#define B_SZ  16
#define EPSF  1e-8f

#define FMA16(W, X0, X1, X2, X3) do { \
  acc[0][0] += (X0)*(W).x; acc[0][1] += (X0)*(W).y; acc[0][2] += (X0)*(W).z; acc[0][3] += (X0)*(W).w; \
  acc[1][0] += (X1)*(W).x; acc[1][1] += (X1)*(W).y; acc[1][2] += (X1)*(W).z; acc[1][3] += (X1)*(W).w; \
  acc[2][0] += (X2)*(W).x; acc[2][1] += (X2)*(W).y; acc[2][2] += (X2)*(W).z; acc[2][3] += (X2)*(W).w; \
  acc[3][0] += (X3)*(W).x; acc[3][1] += (X3)*(W).y; acc[3][2] += (X3)*(W).z; acc[3][3] += (X3)*(W).w; \
} while (0)

// ---------------------------------------------------------------------------
// K1: raw_alpha = softplus(silu(LN(h) @ W1 + b1) @ W2 + b2)   [B*T rows]
// 32 rows/block, 256 threads. LN'd rows in LDS; W1 LDS-staged per BK=16 with
// register prefetch. GEMM: thread = (rg 0..7 -> 4 rows) x (jl 0..31 -> 4 cols).
// ---------------------------------------------------------------------------
__global__ __launch_bounds__(256) void alpha_net_kernel(
    const float* __restrict__ h,
    const float* __restrict__ ln_g, const float* __restrict__ ln_b,
    const float* __restrict__ W1,   const float* __restrict__ b1,
    const float* __restrict__ W2,   const float* __restrict__ b2,
    float* __restrict__ raw_alpha)
{
    __shared__ float xn[32][512];    // 64 KB
    __shared__ float Wt[16][128];    // 8 KB  (72 KB total -> 2 blocks/CU)
    const int tid  = threadIdx.x;
    const int row0 = blockIdx.x * 32;

    // ---- load 32 rows (32*512 f32) as float4, coalesced ----
    const float4* hsrc = (const float4*)(h + (size_t)row0 * D_DIM);
    #pragma unroll
    for (int i = 0; i < 16; ++i) {
        int idx = tid + i * 256;                 // 0..4095
        float4 v = hsrc[idx];
        *(float4*)&xn[idx >> 7][(idx & 127) << 2] = v;
    }
    __syncthreads();

    // ---- LayerNorm in place: 4 waves x 8 rows, contiguous float4 per lane ----
    const int wave = tid >> 6;
    const int lane = tid & 63;
    const int c1 = lane * 4;
    const int c2 = 256 + lane * 4;
    #pragma unroll
    for (int rr = 0; rr < 8; ++rr) {
        int r = wave * 8 + rr;
        float4 a  = *(const float4*)&xn[r][c1];
        float4 bq = *(const float4*)&xn[r][c2];
        float s  = a.x + a.y + a.z + a.w + bq.x + bq.y + bq.z + bq.w;
        float sq = a.x*a.x + a.y*a.y + a.z*a.z + a.w*a.w
                 + bq.x*bq.x + bq.y*bq.y + bq.z*bq.z + bq.w*bq.w;
        #pragma unroll
        for (int off = 32; off >= 1; off >>= 1) {
            s  += __shfl_xor(s,  off);
            sq += __shfl_xor(sq, off);
        }
        float mu  = s * (1.0f / 512.0f);
        float var = sq * (1.0f / 512.0f) - mu * mu;
        float inv = rsqrtf(var + 1e-5f);
        float4 g1 = *(const float4*)&ln_g[c1];
        float4 g2 = *(const float4*)&ln_g[c2];
        float4 o1 = *(const float4*)&ln_b[c1];
        float4 o2 = *(const float4*)&ln_b[c2];
        a.x  = (a.x  - mu) * inv * g1.x + o1.x;
        a.y  = (a.y  - mu) * inv * g1.y + o1.y;
        a.z  = (a.z  - mu) * inv * g1.z + o1.z;
        a.w  = (a.w  - mu) * inv * g1.w + o1.w;
        bq.x = (bq.x - mu) * inv * g2.x + o2.x;
        bq.y = (bq.y - mu) * inv * g2.y + o2.y;
        bq.z = (bq.z - mu) * inv * g2.z + o2.z;
        bq.w = (bq.w - mu) * inv * g2.w + o2.w;
        *(float4*)&xn[r][c1] = a;
        *(float4*)&xn[r][c2] = bq;
    }

    // ---- xn @ W1, W1 LDS-staged (BK=16) + register prefetch ----
    const int jl = tid & 31;
    const int rg = tid >> 5;
    const int j4 = jl * 4;
    const int rbase = rg * 4;
    const int wk0 = tid >> 5;                 // Wt row for slot0 (0..7)
    const int wk1 = (tid + 256) >> 5;         // Wt row for slot1 (8..15)
    const int wc  = (tid & 31) << 2;          // Wt col
    float acc[4][4] = {};
    float4 w0 = *(const float4*)&W1[(size_t)wk0 * HID + wc];
    float4 w1 = *(const float4*)&W1[(size_t)wk1 * HID + wc];
    for (int kc = 0; kc < D_DIM; kc += 16) {
        __syncthreads();                      // prior compute done reading Wt
        *(float4*)&Wt[wk0][wc] = w0;
        *(float4*)&Wt[wk1][wc] = w1;
        if (kc + 16 < D_DIM) {
            w0 = *(const float4*)&W1[(size_t)(kc + 16 + wk0) * HID + wc];
            w1 = *(const float4*)&W1[(size_t)(kc + 16 + wk1) * HID + wc];
        }
        __syncthreads();
        #pragma unroll
        for (int k4 = 0; k4 < 4; ++k4) {
            int k = k4 << 2;
            float4 wA = *(const float4*)&Wt[k + 0][j4];
            float4 wB = *(const float4*)&Wt[k + 1][j4];
            float4 wC = *(const float4*)&Wt[k + 2][j4];
            float4 wD = *(const float4*)&Wt[k + 3][j4];
            float4 x0 = *(const float4*)&xn[rbase + 0][kc + k];
            float4 x1 = *(const float4*)&xn[rbase + 1][kc + k];
            float4 x2 = *(const float4*)&xn[rbase + 2][kc + k];
            float4 x3 = *(const float4*)&xn[rbase + 3][kc + k];
            FMA16(wA, x0.x, x1.x, x2.x, x3.x);
            FMA16(wB, x0.y, x1.y, x2.y, x3.y);
            FMA16(wC, x0.z, x1.z, x2.z, x3.z);
            FMA16(wD, x0.w, x1.w, x2.w, x3.w);
        }
    }

    // ---- +b1, SiLU, dot W2 over this thread's 4 cols, reduce across 32 lanes ----
    float4 b1q = *(const float4*)&b1[j4];
    float4 w2q = *(const float4*)&W2[j4];
    float b2s  = b2[0];
    float srow[4];
    #pragma unroll
    for (int r = 0; r < 4; ++r) {
        float z0 = acc[r][0] + b1q.x;
        float z1 = acc[r][1] + b1q.y;
        float z2 = acc[r][2] + b1q.z;
        float z3 = acc[r][3] + b1q.w;
        float s = z0 / (1.f + expf(-z0)) * w2q.x
                + z1 / (1.f + expf(-z1)) * w2q.y
                + z2 / (1.f + expf(-z2)) * w2q.z
                + z3 / (1.f + expf(-z3)) * w2q.w;
        s += __shfl_xor(s, 16);
        s += __shfl_xor(s, 8);
        s += __shfl_xor(s, 4);
        s += __shfl_xor(s, 2);
        s += __shfl_xor(s, 1);
        srow[r] = s;
    }
    if (jl == 0) {
        #pragma unroll
        for (int r = 0; r < 4; ++r) {
            float z  = srow[r] + b2s;
            // jax softplus = logaddexp(z, 0) = max(z,0) + log1p(exp(-|z|))
            float sp = fmaxf(z, 0.f) + log1pf(expf(-fabsf(z)));
            raw_alpha[row0 + rbase + r] = sp;
        }
    }
}

// ---------------------------------------------------------------------------
// K2a: masked chunk sums S[b][ch] over raw alpha. Grid (4, B), 256 thr.
// ---------------------------------------------------------------------------
__global__ __launch_bounds__(256) void chunk_sum_kernel(
    const float* __restrict__ raw, const int* __restrict__ ilen,
    float* __restrict__ S)
{
    __shared__ float wred[4];
    const int ch = blockIdx.x, b = blockIdx.y;
    const int tid = threadIdx.x;
    const int L = min(ilen[b], T_LEN);
    const int base = ch << 10;
    float local = 0.f;
    #pragma unroll
    for (int i = 0; i < 4; ++i) {
        int t = base + tid + (i << 8);
        if (t < L) local += raw[b * T_LEN + t];
    }
    #pragma unroll
    for (int off = 32; off >= 1; off >>= 1) local += __shfl_xor(local, off);
    if ((tid & 63) == 0) wred[tid >> 6] = local;
    __syncthreads();
    if (tid == 0) S[b * 4 + ch] = wred[0] + wred[1] + wred[2] + wred[3];
}

// ---------------------------------------------------------------------------
// K2b: per (b, chunk): scale raw -> alpha, inclusive scan -> c. Grid (4, B),
// 1024 thr (16 waves). Carry derived from chunk sums (algebraically exact).
// ---------------------------------------------------------------------------
__global__ __launch_bounds__(1024) void scan_chunk_kernel(
    const float* __restrict__ raw, const float* __restrict__ S,
    const int* __restrict__ tgt, const int* __restrict__ ilen,
    float* __restrict__ alpha_out, float* __restrict__ c_out)
{
    __shared__ float wsum_lds[16];
    __shared__ float wscan_lds[16];
    const int ch = blockIdx.x, b = blockIdx.y;
    const int tid  = threadIdx.x;
    const int wid  = tid >> 6;
    const int lane = tid & 63;
    const int L    = min(ilen[b], T_LEN);
    const float Nf = (float)tgt[b];

    float s0 = S[b * 4 + 0], s1 = S[b * 4 + 1], s2 = S[b * 4 + 2], s3 = S[b * 4 + 3];
    float sums  = s0 + s1 + s2 + s3;
    float scale = Nf / (sums + EPSF);
    float uu    = (sums < 10.f * EPSF) ? 1.f : 0.f;
    float unif  = Nf / fmaxf((float)L, 1.f);
    float prefix = (ch > 0 ? s0 : 0.f) + (ch > 1 ? s1 : 0.f) + (ch > 2 ? s2 : 0.f);
    float carry  = (1.f - uu) * scale * prefix
                 + uu * unif * (float)min(L, ch << 10);

    int t = (ch << 10) + tid;
    float m = (t < L) ? 1.f : 0.f;
    float a = (raw[b * T_LEN + t] * m * scale) * (1.f - uu) + m * unif * uu;
    alpha_out[b * T_LEN + t] = a;

    float v = a;
    #pragma unroll
    for (int off = 1; off < 64; off <<= 1) {
        float tv = __shfl_up(v, off);
        if (lane >= off) v += tv;
    }
    if (lane == 63) wsum_lds[wid] = v;
    __syncthreads();
    if (wid == 0 && lane < 16) {
        float s = wsum_lds[lane];
        #pragma unroll
        for (int off = 1; off < 16; off <<= 1) {
            float tv = __shfl_up(s, off);
            if (lane >= off) s += tv;
        }
        wscan_lds[lane] = s;
    }
    __syncthreads();
    float woff = (wid > 0) ? wscan_lds[wid - 1] : 0.f;
    c_out[b * T_LEN + t] = carry + woff + v;
}

// ---------------------------------------------------------------------------
// K3: per (b, bin n): binary-search contiguous frame range, accumulate
// hw[b,n,:] = sum_t w*h[b,t,:], plus cif_mass / frame_durations / token_mask.
// float4 cols, even/odd frame split across thread halves (2 frames in flight).
// ---------------------------------------------------------------------------
__global__ __launch_bounds__(256) void cif_gather_kernel(
    const float* __restrict__ h, const float* __restrict__ alpha,
    const float* __restrict__ c_arr,
    const int* __restrict__ tgt, const int* __restrict__ ilen,
    float* __restrict__ hw, float* __restrict__ fd_out,
    float* __restrict__ cm_out, float* __restrict__ tm_out)
{
    __shared__ float part[514];        // 512 col partials + wsum,fdsum
    const int n   = blockIdx.x;
    const int b   = blockIdx.y;
    const int tid = threadIdx.x;
    const int oidx = b * N_MAX + n;
    if (n >= tgt[b]) {
        if (tid == 0) { fd_out[oidx] = 0.f; cm_out[oidx] = 0.f; tm_out[oidx] = 0.f; }
        return;   // hw row left as (finite) poison; K4 masks it to zero
    }
    const int L = min(ilen[b], T_LEN);
    const float* cb = c_arr + b * T_LEN;
    const float* ab = alpha + b * T_LEN;
    const float nf  = (float)n;
    const float nf1 = nf + 1.0f;

    // first t with c[t] > n
    int lo = 0, hi = T_LEN;
    while (lo < hi) { int mid = (lo + hi) >> 1; if (cb[mid] > nf) hi = mid; else lo = mid + 1; }
    const int t0 = lo;
    // first t with c[t] >= n+1  (== last contributing frame, since c_prev[t]=c[t-1])
    lo = 0; hi = T_LEN;
    while (lo < hi) { int mid = (lo + hi) >> 1; if (cb[mid] >= nf1) hi = mid; else lo = mid + 1; }
    int t1 = min(lo, L - 1);

    const int par = tid >> 7;          // 0: even frames, 1: odd frames
    const int c4  = (tid & 127) << 2;  // float column base
    float4 acc = make_float4(0.f, 0.f, 0.f, 0.f);
    float wsum = 0.f, fdsum = 0.f;
    const float* hb = h + (size_t)(b * T_LEN) * D_DIM;
    for (int t = t0 + par; t <= t1; t += 2) {
        float a = ab[t], c = cb[t];
        float cp = c - a;                               // c_prev, same arithmetic as ref
        float w  = fmaxf(fminf(c, nf1) - fmaxf(cp, nf), 0.f);
        wsum  += w;
        fdsum += w / (a + EPSF);
        const float4 hv = *(const float4*)(hb + (size_t)t * D_DIM + c4);
        acc.x += w * hv.x;
        acc.y += w * hv.y;
        acc.z += w * hv.z;
        acc.w += w * hv.w;
    }
    if (par == 1) {
        *(float4*)&part[c4] = acc;
        if (tid == 128) { part[512] = wsum; part[513] = fdsum; }
    }
    __syncthreads();
    if (par == 0) {
        float4 p = *(const float4*)&part[c4];
        acc.x += p.x; acc.y += p.y; acc.z += p.z; acc.w += p.w;
        *(float4*)(hw + (size_t)oidx * D_DIM + c4) = acc;
        if (tid == 0) {
            fd_out[oidx] = fdsum + part[513];
            cm_out[oidx] = wsum + part[512];
            tm_out[oidx] = 1.f;
        }
    }
}

// ---------------------------------------------------------------------------
// K4: tokens = (hw @ Wv + cif_mass*bv) * token_mask.  M=6400, N=512, K=512.
// 32x128 tile per block, 256 threads; Wv LDS-staged per BK=16 with register
// prefetch (identical inner structure to K1).
// ---------------------------------------------------------------------------
__global__ __launch_bounds__(256) void token_gemm_kernel(
    const float* __restrict__ hw, const float* __restrict__ Wv,
    const float* __restrict__ bv, const float* __restrict__ cm,
    const int* __restrict__ tgt, float* __restrict__ tokens)
{
    __shared__ float As[32][512];    // 64 KB
    __shared__ float Wt[16][128];    // 8 KB
    const int tid  = threadIdx.x;
    const int row0 = blockIdx.x * 32;
    const int colb = blockIdx.y * 128;

    const float4* src = (const float4*)(hw + (size_t)row0 * D_DIM);
    #pragma unroll
    for (int i = 0; i < 16; ++i) {
        int idx = tid + i * 256;
        float4 v = src[idx];
        *(float4*)&As[idx >> 7][(idx & 127) << 2] = v;
    }

    const int jl = tid & 31;
    const int rg = tid >> 5;
    const int j4 = jl * 4;
    const int col = colb + j4;
    const int rbase = rg * 4;
    const int wk0 = tid >> 5;
    const int wk1 = (tid + 256) >> 5;
    const int wc  = (tid & 31) << 2;
    float acc[4][4] = {};
    float4 w0 = *(const float4*)&Wv[(size_t)wk0 * D_DIM + colb + wc];
    float4 w1 = *(const float4*)&Wv[(size_t)wk1 * D_DIM + colb + wc];
    for (int kc = 0; kc < D_DIM; kc += 16) {
        __syncthreads();                      // prior compute done (iter0: As ready)
        *(float4*)&Wt[wk0][wc] = w0;
        *(float4*)&Wt[wk1][wc] = w1;
        if (kc + 16 < D_DIM) {
            w0 = *(const float4*)&Wv[(size_t)(kc + 16 + wk0) * D_DIM + colb + wc];
            w1 = *(const float4*)&Wv[(size_t)(kc + 16 + wk1) * D_DIM + colb + wc];
        }
        __syncthreads();
        #pragma unroll
        for (int k4 = 0; k4 < 4; ++k4) {
            int k = k4 << 2;
            float4 wA = *(const float4*)&Wt[k + 0][j4];
            float4 wB = *(const float4*)&Wt[k + 1][j4];
            float4 wC = *(const float4*)&Wt[k + 2][j4];
            float4 wD = *(const float4*)&Wt[k + 3][j4];
            float4 x0 = *(const float4*)&As[rbase + 0][kc + k];
            float4 x1 = *(const float4*)&As[rbase + 1][kc + k];
            float4 x2 = *(const float4*)&As[rbase + 2][kc + k];
            float4 x3 = *(const float4*)&As[rbase + 3][kc + k];
            FMA16(wA, x0.x, x1.x, x2.x, x3.x);
            FMA16(wB, x0.y, x1.y, x2.y, x3.y);
            FMA16(wC, x0.z, x1.z, x2.z, x3.z);
            FMA16(wD, x0.w, x1.w, x2.w, x3.w);
        }
    }

    float4 bq = *(const float4*)&bv[col];
    #pragma unroll
    for (int r = 0; r < 4; ++r) {
        int row = row0 + rbase + r;
        int bb  = row / N_MAX;
        int nn  = row - bb * N_MAX;
        float m  = (nn < tgt[bb]) ? 1.f : 0.f;
        float wm = cm[row];                     // already masked (0 for masked bins)
        float4 o;
        o.x = m * (acc[r][0] + wm * bq.x);
        o.y = m * (acc[r][1] + wm * bq.y);
        o.z = m * (acc[r][2] + wm * bq.z);
        o.w = m * (acc[r][3] + wm * bq.w);
        *(float4*)&tokens[(size_t)row * D_DIM + col] = o;
    }
}

// ---------------------------------------------------------------------------
extern "C" void kernel_launch(void* const* d_in, const int* in_sizes, int n_in,
                              void* d_out, int out_size, void* d_ws, size_t ws_size,
                              hipStream_t stream)
{
    (void)in_sizes; (void)n_in; (void)out_size; (void)ws_size;
    const float* h    = (const float*)d_in[0];
    const int*   tgt  = (const int*)  d_in[1];
    const int*   ilen = (const int*)  d_in[2];
    const float* lng  = (const float*)d_in[3];
    const float* lnb  = (const float*)d_in[4];
    const float* W1   = (const float*)d_in[5];
    const float* b1   = (const float*)d_in[6];
    const float* W2   = (const float*)d_in[7];
    const float* b2   = (const float*)d_in[8];
    const float* Wv   = (const float*)d_in[9];
    const float* bv   = (const float*)d_in[10];

    float* out    = (float*)d_out;
    float* tokens = out;                                        // [B, N_MAX, V]
    float* fd     = tokens + (size_t)B_SZ * N_MAX * D_DIM;      // [B, N_MAX]
    float* cm     = fd + B_SZ * N_MAX;                          // [B, N_MAX]
    float* tm     = cm + B_SZ * N_MAX;                          // [B, N_MAX]
    float* alpha  = tm + B_SZ * N_MAX;                          // [B, T]
    float* raw    = alpha + B_SZ * T_LEN;                       // [B, T]

    float* c_ws = (float*)d_ws;                                 // [B, T]
    float* hw   = c_ws + (size_t)B_SZ * T_LEN;                  // [B*N_MAX, D]
    float* S    = hw + (size_t)B_SZ * N_MAX * D_DIM;            // [B, 4] chunk sums

    alpha_net_kernel<<<(B_SZ * T_LEN) / 32, 256, 0, stream>>>(h, lng, lnb, W1, b1, W2, b2, raw);
    chunk_sum_kernel<<<dim3(4, B_SZ), 256, 0, stream>>>(raw, ilen, S);
    scan_chunk_kernel<<<dim3(4, B_SZ), 1024, 0, stream>>>(raw, S, tgt, ilen, alpha, c_ws);
    cif_gather_kernel<<<dim3(N_MAX, B_SZ), 256, 0, stream>>>(h, alpha, c_ws, tgt, ilen,
                                                             hw, fd, cm, tm);
    token_gemm_kernel<<<dim3((B_SZ * N_MAX) / 32, 4), 256, 0, stream>>>(hw, Wv, bv, cm, tgt, tokens);
}

// Round 8
// 410.281 us; speedup vs baseline: 1.4603x; 1.0821x over previous
//
#include <hip/hip_runtime.h>
#include <math.h>

// CIF kernel. Key algebra: tokens[b,n,:] = (sum_t w[b,t,n] * h[b,t,:]) @ Wv + cif_mass[b,n]*bv
// so we never materialize v = h@Wv (34 GFLOP) nor dense w (26 TFLOP einsum).
// w is band-sparse: c = cumsum(alpha) is monotone -> each bin n covers a contiguous
// frame range found by binary search on c.
//
// R7 (resubmit; bench was an acquisition timeout): fp32-VALU GEMM is LDS-issue-bound
// (R6: 1024 ds_read_b128/thread x 12cyc on the shared per-CU LDS pipe ~= 164us >>
// 55us FMA floor; no fp32 tiling reaches the needed 24:1 FMA:read). Switch both
// GEMMs to 16x16x32 bf16 MFMA:
//  - alpha_net: bf16x3 split (hi/lo, 3 MFMAs) keeps alpha-path error ~2^-16 rel
//    (fd = w/(alpha+eps) is ill-conditioned; plain bf16 too risky).
//  - token_gemm: plain bf16 (errors don't feed c/fd; tokens err ~1e-3 << 0.0625).
//  - k-layout inside fragments is irrelevant if A and B use the SAME mapping
//    (sum_k a_k b_k invariant); only lane&15 m/n mapping + verified C/D layout matter.
//  - weights pre-transposed+split to bf16 by small tile kernels (k-contiguous rows).
//  - K3 writes hw directly as bf16 (K4's A operand).

#define T_LEN 4096
#define D_DIM 512
#define HID   128
#define N_MAX 400
#define B_SZ  16
#define EPSF  1e-8f

typedef __attribute__((ext_vector_type(8))) short bf16x8;
typedef __attribute__((ext_vector_type(4))) float f32x4;

__device__ __forceinline__ unsigned short f2bf(float x) {
    unsigned u = __float_as_uint(x);
    unsigned r = (u + 0x7FFFu + ((u >> 16) & 1u)) >> 16;   // RNE
    return (unsigned short)r;
}
__device__ __forceinline__ float bf2f(unsigned short h) {
    return __uint_as_float(((unsigned)h) << 16);
}

// ---------------------------------------------------------------------------
// P0: tile transpose + bf16 split:  out_hi[n][k] = bf16(in[k][n]), out_lo = residual.
// in is KxN row-major. Grid (K/64, N/64), 256 thr, LDS 64x65 tile.
// ---------------------------------------------------------------------------
__global__ __launch_bounds__(256) void transpose_split_kernel(
    const float* __restrict__ in, unsigned short* __restrict__ out_hi,
    unsigned short* __restrict__ out_lo, int K, int N)
{
    __shared__ float tile[64][65];
    const int tid = threadIdx.x;
    const int k0 = blockIdx.x * 64, n0 = blockIdx.y * 64;
    #pragma unroll
    for (int i = 0; i < 16; ++i) {
        int idx = tid + i * 256;
        tile[idx >> 6][idx & 63] = in[(size_t)(k0 + (idx >> 6)) * N + n0 + (idx & 63)];
    }
    __syncthreads();
    #pragma unroll
    for (int i = 0; i < 16; ++i) {
        int idx = tid + i * 256;
        int nr = idx >> 6, kc = idx & 63;
        float x = tile[kc][nr];
        unsigned short hi = f2bf(x);
        out_hi[(size_t)(n0 + nr) * K + k0 + kc] = hi;
        if (out_lo) out_lo[(size_t)(n0 + nr) * K + k0 + kc] = f2bf(x - bf2f(hi));
    }
}

// ---------------------------------------------------------------------------
// K1: raw_alpha = softplus(silu(LN(h) @ W1 + b1) @ W2 + b2)   [B*T rows]
// 32 rows/block, 256 thr (4 waves). LN loads h coalesced from GLOBAL (no f32
// staging), writes bf16 hi/lo planes to LDS (row stride 2064 B: banks spread,
// hi at +0, lo at +1024). MFMA: wave=(rt,ch): 16 rows x 64 cols = 4 n-tiles,
// bf16x3 (3 MFMA per tile per k-step), B-frags from global W1t (L2-resident).
// Epilogue: lane owns 4 rows x 4 cols -> silu*W2 partial, shfl over 16 col-
// lanes, cross-ch add via LDS, softplus.
// ---------------------------------------------------------------------------
__global__ __launch_bounds__(256) void alpha_net_kernel(
    const float* __restrict__ h,
    const float* __restrict__ ln_g, const float* __restrict__ ln_b,
    const unsigned short* __restrict__ W1t_hi, const unsigned short* __restrict__ W1t_lo,
    const float* __restrict__ b1,
    const float* __restrict__ W2,   const float* __restrict__ b2,
    float* __restrict__ raw_alpha)
{
    __shared__ char planes[32 * 2064];     // per row: [hi 1024B][lo 1024B][pad 16B]
    __shared__ float part2[2][2][16];      // [ch][rt][row16]
    const int tid  = threadIdx.x;
    const int row0 = blockIdx.x * 32;
    const int wave = tid >> 6;
    const int lane = tid & 63;

    // ---- LN: wave handles 8 rows; lane covers cols c1..c1+3 and c2..c2+3 ----
    const int c1 = lane * 4;
    const int c2 = 256 + lane * 4;
    float4 g1 = *(const float4*)&ln_g[c1];
    float4 g2 = *(const float4*)&ln_g[c2];
    float4 o1 = *(const float4*)&ln_b[c1];
    float4 o2 = *(const float4*)&ln_b[c2];
    float4 av[8], bv8[8];
    const int rbase8 = wave * 8;
    #pragma unroll
    for (int rr = 0; rr < 8; ++rr) {
        const float* hrow = h + (size_t)(row0 + rbase8 + rr) * D_DIM;
        float4 a  = *(const float4*)(hrow + c1);
        float4 bq = *(const float4*)(hrow + c2);
        float s  = a.x + a.y + a.z + a.w + bq.x + bq.y + bq.z + bq.w;
        float sq = a.x*a.x + a.y*a.y + a.z*a.z + a.w*a.w
                 + bq.x*bq.x + bq.y*bq.y + bq.z*bq.z + bq.w*bq.w;
        #pragma unroll
        for (int off = 32; off >= 1; off >>= 1) {
            s  += __shfl_xor(s,  off);
            sq += __shfl_xor(sq, off);
        }
        float mu  = s * (1.0f / 512.0f);
        float var = sq * (1.0f / 512.0f) - mu * mu;
        float inv = rsqrtf(var + 1e-5f);
        a.x  = (a.x  - mu) * inv * g1.x + o1.x;
        a.y  = (a.y  - mu) * inv * g1.y + o1.y;
        a.z  = (a.z  - mu) * inv * g1.z + o1.z;
        a.w  = (a.w  - mu) * inv * g1.w + o1.w;
        bq.x = (bq.x - mu) * inv * g2.x + o2.x;
        bq.y = (bq.y - mu) * inv * g2.y + o2.y;
        bq.z = (bq.z - mu) * inv * g2.z + o2.z;
        bq.w = (bq.w - mu) * inv * g2.w + o2.w;
        av[rr] = a; bv8[rr] = bq;
    }
    // ---- write hi/lo bf16 planes ----
    #pragma unroll
    for (int rr = 0; rr < 8; ++rr) {
        char* rb = planes + (rbase8 + rr) * 2064;
        float4 a = av[rr], bq = bv8[rr];
        ushort4 ha = make_ushort4(f2bf(a.x), f2bf(a.y), f2bf(a.z), f2bf(a.w));
        ushort4 hb = make_ushort4(f2bf(bq.x), f2bf(bq.y), f2bf(bq.z), f2bf(bq.w));
        ushort4 la = make_ushort4(f2bf(a.x - bf2f(ha.x)), f2bf(a.y - bf2f(ha.y)),
                                  f2bf(a.z - bf2f(ha.z)), f2bf(a.w - bf2f(ha.w)));
        ushort4 lb = make_ushort4(f2bf(bq.x - bf2f(hb.x)), f2bf(bq.y - bf2f(hb.y)),
                                  f2bf(bq.z - bf2f(hb.z)), f2bf(bq.w - bf2f(hb.w)));
        *(ushort4*)(rb + 2 * c1)        = ha;
        *(ushort4*)(rb + 2 * c2)        = hb;
        *(ushort4*)(rb + 1024 + 2 * c1) = la;
        *(ushort4*)(rb + 1024 + 2 * c2) = lb;
    }
    __syncthreads();

    // ---- MFMA: wave -> (rt=wave>>1 rows, ch=wave&1 col-half) ----
    const int rt = wave >> 1, ch = wave & 1;
    const int lr = lane & 15, lg = lane >> 4;
    const char* aBase = planes + (rt * 16 + lr) * 2064;
    f32x4 acc[4];
    #pragma unroll
    for (int nt = 0; nt < 4; ++nt) acc[nt] = (f32x4){0.f, 0.f, 0.f, 0.f};
    for (int ks = 0; ks < 16; ++ks) {
        const int cofs = (4 * ks + lg) * 16;
        bf16x8 ahi = *(const bf16x8*)(aBase + cofs);
        bf16x8 alo = *(const bf16x8*)(aBase + 1024 + cofs);
        const int kofs = ks * 32 + lg * 8;
        #pragma unroll
        for (int nt = 0; nt < 4; ++nt) {
            int n = ch * 64 + nt * 16 + lr;
            bf16x8 bhi = *(const bf16x8*)(W1t_hi + (size_t)n * D_DIM + kofs);
            bf16x8 blo = *(const bf16x8*)(W1t_lo + (size_t)n * D_DIM + kofs);
            acc[nt] = __builtin_amdgcn_mfma_f32_16x16x32_bf16(ahi, bhi, acc[nt], 0, 0, 0);
            acc[nt] = __builtin_amdgcn_mfma_f32_16x16x32_bf16(ahi, blo, acc[nt], 0, 0, 0);
            acc[nt] = __builtin_amdgcn_mfma_f32_16x16x32_bf16(alo, bhi, acc[nt], 0, 0, 0);
        }
    }

    // ---- epilogue: +b1, SiLU, *W2, reduce over this wave's 64 cols ----
    float p[4] = {0.f, 0.f, 0.f, 0.f};
    #pragma unroll
    for (int nt = 0; nt < 4; ++nt) {
        int n = ch * 64 + nt * 16 + lr;
        float b1v = b1[n], w2v = W2[n];
        #pragma unroll
        for (int j = 0; j < 4; ++j) {
            float z = acc[nt][j] + b1v;
            p[j] += z / (1.f + expf(-z)) * w2v;
        }
    }
    #pragma unroll
    for (int j = 0; j < 4; ++j) {
        p[j] += __shfl_xor(p[j], 1);
        p[j] += __shfl_xor(p[j], 2);
        p[j] += __shfl_xor(p[j], 4);
        p[j] += __shfl_xor(p[j], 8);
    }
    if (lr == 0) {
        #pragma unroll
        for (int j = 0; j < 4; ++j) part2[ch][rt][lg * 4 + j] = p[j];
    }
    __syncthreads();
    if (tid < 32) {
        int r16 = tid & 15, rt2 = tid >> 4;
        float z = part2[0][rt2][r16] + part2[1][rt2][r16] + b2[0];
        // jax softplus = max(z,0) + log1p(exp(-|z|))
        float sp = fmaxf(z, 0.f) + log1pf(expf(-fabsf(z)));
        raw_alpha[row0 + rt2 * 16 + r16] = sp;
    }
}

// ---------------------------------------------------------------------------
// K2a: masked chunk sums S[b][ch] over raw alpha. Grid (4, B), 256 thr.
// ---------------------------------------------------------------------------
__global__ __launch_bounds__(256) void chunk_sum_kernel(
    const float* __restrict__ raw, const int* __restrict__ ilen,
    float* __restrict__ S)
{
    __shared__ float wred[4];
    const int ch = blockIdx.x, b = blockIdx.y;
    const int tid = threadIdx.x;
    const int L = min(ilen[b], T_LEN);
    const int base = ch << 10;
    float local = 0.f;
    #pragma unroll
    for (int i = 0; i < 4; ++i) {
        int t = base + tid + (i << 8);
        if (t < L) local += raw[b * T_LEN + t];
    }
    #pragma unroll
    for (int off = 32; off >= 1; off >>= 1) local += __shfl_xor(local, off);
    if ((tid & 63) == 0) wred[tid >> 6] = local;
    __syncthreads();
    if (tid == 0) S[b * 4 + ch] = wred[0] + wred[1] + wred[2] + wred[3];
}

// ---------------------------------------------------------------------------
// K2b: per (b, chunk): scale raw -> alpha, inclusive scan -> c. Grid (4, B),
// 1024 thr (16 waves). Carry derived from chunk sums (algebraically exact).
// ---------------------------------------------------------------------------
__global__ __launch_bounds__(1024) void scan_chunk_kernel(
    const float* __restrict__ raw, const float* __restrict__ S,
    const int* __restrict__ tgt, const int* __restrict__ ilen,
    float* __restrict__ alpha_out, float* __restrict__ c_out)
{
    __shared__ float wsum_lds[16];
    __shared__ float wscan_lds[16];
    const int ch = blockIdx.x, b = blockIdx.y;
    const int tid  = threadIdx.x;
    const int wid  = tid >> 6;
    const int lane = tid & 63;
    const int L    = min(ilen[b], T_LEN);
    const float Nf = (float)tgt[b];

    float s0 = S[b * 4 + 0], s1 = S[b * 4 + 1], s2 = S[b * 4 + 2], s3 = S[b * 4 + 3];
    float sums  = s0 + s1 + s2 + s3;
    float scale = Nf / (sums + EPSF);
    float uu    = (sums < 10.f * EPSF) ? 1.f : 0.f;
    float unif  = Nf / fmaxf((float)L, 1.f);
    float prefix = (ch > 0 ? s0 : 0.f) + (ch > 1 ? s1 : 0.f) + (ch > 2 ? s2 : 0.f);
    float carry  = (1.f - uu) * scale * prefix
                 + uu * unif * (float)min(L, ch << 10);

    int t = (ch << 10) + tid;
    float m = (t < L) ? 1.f : 0.f;
    float a = (raw[b * T_LEN + t] * m * scale) * (1.f - uu) + m * unif * uu;
    alpha_out[b * T_LEN + t] = a;

    float v = a;
    #pragma unroll
    for (int off = 1; off < 64; off <<= 1) {
        float tv = __shfl_up(v, off);
        if (lane >= off) v += tv;
    }
    if (lane == 63) wsum_lds[wid] = v;
    __syncthreads();
    if (wid == 0 && lane < 16) {
        float s = wsum_lds[lane];
        #pragma unroll
        for (int off = 1; off < 16; off <<= 1) {
            float tv = __shfl_up(s, off);
            if (lane >= off) s += tv;
        }
        wscan_lds[lane] = s;
    }
    __syncthreads();
    float woff = (wid > 0) ? wscan_lds[wid - 1] : 0.f;
    c_out[b * T_LEN + t] = carry + woff + v;
}

// ---------------------------------------------------------------------------
// K3: per (b, bin n): binary-search contiguous frame range, accumulate
// hw[b,n,:] = sum_t w*h[b,t,:] (written as bf16 for K4's MFMA A operand),
// plus cif_mass / frame_durations / token_mask.
// ---------------------------------------------------------------------------
__global__ __launch_bounds__(256) void cif_gather_kernel(
    const float* __restrict__ h, const float* __restrict__ alpha,
    const float* __restrict__ c_arr,
    const int* __restrict__ tgt, const int* __restrict__ ilen,
    unsigned short* __restrict__ hwb, float* __restrict__ fd_out,
    float* __restrict__ cm_out, float* __restrict__ tm_out)
{
    __shared__ float part[514];        // 512 col partials + wsum,fdsum
    const int n   = blockIdx.x;
    const int b   = blockIdx.y;
    const int tid = threadIdx.x;
    const int oidx = b * N_MAX + n;
    if (n >= tgt[b]) {
        if (tid == 0) { fd_out[oidx] = 0.f; cm_out[oidx] = 0.f; tm_out[oidx] = 0.f; }
        return;   // hwb row left as (finite bf16) poison; K4 masks it to zero
    }
    const int L = min(ilen[b], T_LEN);
    const float* cb = c_arr + b * T_LEN;
    const float* ab = alpha + b * T_LEN;
    const float nf  = (float)n;
    const float nf1 = nf + 1.0f;

    // first t with c[t] > n
    int lo = 0, hi = T_LEN;
    while (lo < hi) { int mid = (lo + hi) >> 1; if (cb[mid] > nf) hi = mid; else lo = mid + 1; }
    const int t0 = lo;
    // first t with c[t] >= n+1  (== last contributing frame, since c_prev[t]=c[t-1])
    lo = 0; hi = T_LEN;
    while (lo < hi) { int mid = (lo + hi) >> 1; if (cb[mid] >= nf1) hi = mid; else lo = mid + 1; }
    int t1 = min(lo, L - 1);

    const int par = tid >> 7;          // 0: even frames, 1: odd frames
    const int c4  = (tid & 127) << 2;  // float column base
    float4 acc = make_float4(0.f, 0.f, 0.f, 0.f);
    float wsum = 0.f, fdsum = 0.f;
    const float* hb = h + (size_t)(b * T_LEN) * D_DIM;
    for (int t = t0 + par; t <= t1; t += 2) {
        float a = ab[t], c = cb[t];
        float cp = c - a;                               // c_prev, same arithmetic as ref
        float w  = fmaxf(fminf(c, nf1) - fmaxf(cp, nf), 0.f);
        wsum  += w;
        fdsum += w / (a + EPSF);
        const float4 hv = *(const float4*)(hb + (size_t)t * D_DIM + c4);
        acc.x += w * hv.x;
        acc.y += w * hv.y;
        acc.z += w * hv.z;
        acc.w += w * hv.w;
    }
    if (par == 1) {
        *(float4*)&part[c4] = acc;
        if (tid == 128) { part[512] = wsum; part[513] = fdsum; }
    }
    __syncthreads();
    if (par == 0) {
        float4 p = *(const float4*)&part[c4];
        acc.x += p.x; acc.y += p.y; acc.z += p.z; acc.w += p.w;
        *(ushort4*)(hwb + (size_t)oidx * D_DIM + c4) =
            make_ushort4(f2bf(acc.x), f2bf(acc.y), f2bf(acc.z), f2bf(acc.w));
        if (tid == 0) {
            fd_out[oidx] = fdsum + part[513];
            cm_out[oidx] = wsum + part[512];
            tm_out[oidx] = 1.f;
        }
    }
}

// ---------------------------------------------------------------------------
// K4: tokens = (hw @ Wv + cif_mass*bv) * token_mask.  M=6400, N=512, K=512.
// Plain bf16 MFMA. Grid (100, 4); block 64 rows x 128 cols; wave rt -> 16 rows
// x 8 n-tiles. A from hwb (global bf16), B from Wvt (global bf16, L2-resident).
// No LDS -> high occupancy hides VMEM latency.
// ---------------------------------------------------------------------------
__global__ __launch_bounds__(256) void token_gemm_kernel(
    const unsigned short* __restrict__ hwb, const unsigned short* __restrict__ Wvt,
    const float* __restrict__ bv, const float* __restrict__ cm,
    const int* __restrict__ tgt, float* __restrict__ tokens)
{
    const int tid  = threadIdx.x;
    const int wave = tid >> 6;
    const int lane = tid & 63;
    const int lr = lane & 15, lg = lane >> 4;
    const int arow = blockIdx.x * 64 + wave * 16 + lr;
    const int colb = blockIdx.y * 128;

    f32x4 acc[8];
    #pragma unroll
    for (int nt = 0; nt < 8; ++nt) acc[nt] = (f32x4){0.f, 0.f, 0.f, 0.f};
    for (int ks = 0; ks < 16; ++ks) {
        const int kofs = ks * 32 + lg * 8;
        bf16x8 a = *(const bf16x8*)(hwb + (size_t)arow * D_DIM + kofs);
        #pragma unroll
        for (int nt = 0; nt < 8; ++nt) {
            int n = colb + nt * 16 + lr;
            bf16x8 bq = *(const bf16x8*)(Wvt + (size_t)n * D_DIM + kofs);
            acc[nt] = __builtin_amdgcn_mfma_f32_16x16x32_bf16(a, bq, acc[nt], 0, 0, 0);
        }
    }

    // epilogue: lane owns rows (lg*4+j) of its wave's 16-row tile, col lr per tile
    float cmr[4], mr[4];
    int   rr[4];
    #pragma unroll
    for (int j = 0; j < 4; ++j) {
        int r = blockIdx.x * 64 + wave * 16 + lg * 4 + j;
        int bb = r / N_MAX;
        int nn = r - bb * N_MAX;
        rr[j] = r;
        mr[j] = (nn < tgt[bb]) ? 1.f : 0.f;
        cmr[j] = cm[r];
    }
    #pragma unroll
    for (int nt = 0; nt < 8; ++nt) {
        int col = colb + nt * 16 + lr;
        float bvv = bv[col];
        #pragma unroll
        for (int j = 0; j < 4; ++j)
            tokens[(size_t)rr[j] * D_DIM + col] = mr[j] * (acc[nt][j] + cmr[j] * bvv);
    }
}

// ---------------------------------------------------------------------------
extern "C" void kernel_launch(void* const* d_in, const int* in_sizes, int n_in,
                              void* d_out, int out_size, void* d_ws, size_t ws_size,
                              hipStream_t stream)
{
    (void)in_sizes; (void)n_in; (void)out_size; (void)ws_size;
    const float* h    = (const float*)d_in[0];
    const int*   tgt  = (const int*)  d_in[1];
    const int*   ilen = (const int*)  d_in[2];
    const float* lng  = (const float*)d_in[3];
    const float* lnb  = (const float*)d_in[4];
    const float* W1   = (const float*)d_in[5];
    const float* b1   = (const float*)d_in[6];
    const float* W2   = (const float*)d_in[7];
    const float* b2   = (const float*)d_in[8];
    const float* Wv   = (const float*)d_in[9];
    const float* bv   = (const float*)d_in[10];

    float* out    = (float*)d_out;
    float* tokens = out;                                        // [B, N_MAX, V]
    float* fd     = tokens + (size_t)B_SZ * N_MAX * D_DIM;      // [B, N_MAX]
    float* cm     = fd + B_SZ * N_MAX;                          // [B, N_MAX]
    float* tm     = cm + B_SZ * N_MAX;                          // [B, N_MAX]
    float* alpha  = tm + B_SZ * N_MAX;                          // [B, T]
    float* raw    = alpha + B_SZ * T_LEN;                       // [B, T]

    float* c_ws = (float*)d_ws;                                 // [B, T]
    unsigned short* hwb    = (unsigned short*)(c_ws + B_SZ * T_LEN);   // [B*N_MAX, D] bf16
    unsigned short* W1t_hi = hwb + (size_t)B_SZ * N_MAX * D_DIM;       // [HID, D] bf16
    unsigned short* W1t_lo = W1t_hi + (size_t)HID * D_DIM;
    unsigned short* Wvt    = W1t_lo + (size_t)HID * D_DIM;             // [D, D] bf16
    float* S = (float*)(Wvt + (size_t)D_DIM * D_DIM);                  // [B, 4] chunk sums

    transpose_split_kernel<<<dim3(8, 2), 256, 0, stream>>>(W1, W1t_hi, W1t_lo, D_DIM, HID);
    transpose_split_kernel<<<dim3(8, 8), 256, 0, stream>>>(Wv, Wvt, (unsigned short*)nullptr,
                                                           D_DIM, D_DIM);
    alpha_net_kernel<<<(B_SZ * T_LEN) / 32, 256, 0, stream>>>(h, lng, lnb, W1t_hi, W1t_lo,
                                                              b1, W2, b2, raw);
    chunk_sum_kernel<<<dim3(4, B_SZ), 256, 0, stream>>>(raw, ilen, S);
    scan_chunk_kernel<<<dim3(4, B_SZ), 1024, 0, stream>>>(raw, S, tgt, ilen, alpha, c_ws);
    cif_gather_kernel<<<dim3(N_MAX, B_SZ), 256, 0, stream>>>(h, alpha, c_ws, tgt, ilen,
                                                             hwb, fd, cm, tm);
    token_gemm_kernel<<<dim3(100, 4), 256, 0, stream>>>(hwb, Wvt, bv, cm, tgt, tokens);
}

// Round 10
// 331.425 us; speedup vs baseline: 1.8078x; 1.2379x over previous
//
#include <hip/hip_runtime.h>
#include <math.h>

// CIF kernel. tokens[b,n,:] = (sum_t w[b,t,n]*h[b,t,:]) @ Wv + cif_mass[b,n]*bv.
// w band-sparse via cumsum binary search. Both GEMMs on 16x16x32 bf16 MFMA
// (alpha_net bf16x3 hi/lo split for the ill-conditioned alpha path).
//
// R9 (resubmit; bench was an acquisition timeout): R8 showed MfmaUtil 6%/VALU
// 15%/HBM 5% -> latency-bound on B-fragment gathers (16-segment, 1KB-strided
// rows; 1.5 MFMA per gather). Fix:
//  (a) fragment-major B: pre-pack W so each (n-tile,ks) fragment is 64x16B
//      CONTIGUOUS -> every B load = one coalesced 1KB txn. Both GEMMs.
//  (b) alpha_net wave = 32 rows x 32 cols (was 16x64): halves B traffic,
//      doubles MFMA:B-load ratio to 3:1.

#define T_LEN 4096
#define D_DIM 512
#define HID   128
#define N_MAX 400
#define B_SZ  16
#define EPSF  1e-8f

typedef __attribute__((ext_vector_type(8))) short bf16x8;
typedef __attribute__((ext_vector_type(4))) float f32x4;

__device__ __forceinline__ unsigned short f2bf(float x) {
    unsigned u = __float_as_uint(x);
    unsigned r = (u + 0x7FFFu + ((u >> 16) & 1u)) >> 16;   // RNE
    return (unsigned short)r;
}
__device__ __forceinline__ float bf2f(unsigned short h) {
    return __uint_as_float(((unsigned)h) << 16);
}

// ---------------------------------------------------------------------------
// P0: fragment-major bf16 pack of KxN row-major f32 matrix (optional lo plane).
// out[((ntg*(K/32)+ks)*64+lane)*8+e] = bf16(in[(ks*32+(lane>>4)*8+e)*N + ntg*16+(lane&15)])
// One 8-elem fragment per thread; strided reads but tiny matrices (runs ~us).
// ---------------------------------------------------------------------------
__global__ __launch_bounds__(256) void frag_pack_kernel(
    const float* __restrict__ in, unsigned short* __restrict__ out_hi,
    unsigned short* __restrict__ out_lo, int K, int N)
{
    const int idx = blockIdx.x * 256 + threadIdx.x;
    const int nks = K >> 5;
    const int total = (N >> 4) * nks * 64;
    if (idx >= total) return;
    const int lane = idx & 63;
    const int ks   = (idx >> 6) % nks;
    const int ntg  = idx / (nks << 6);
    const int n  = ntg * 16 + (lane & 15);
    const int k0 = ks * 32 + (lane >> 4) * 8;
    unsigned short hv[8], lv[8];
    #pragma unroll
    for (int e = 0; e < 8; ++e) {
        float x = in[(size_t)(k0 + e) * N + n];
        unsigned short hi = f2bf(x);
        hv[e] = hi;
        lv[e] = f2bf(x - bf2f(hi));
    }
    *(ushort4*)(out_hi + (size_t)idx * 8)     = make_ushort4(hv[0], hv[1], hv[2], hv[3]);
    *(ushort4*)(out_hi + (size_t)idx * 8 + 4) = make_ushort4(hv[4], hv[5], hv[6], hv[7]);
    if (out_lo) {
        *(ushort4*)(out_lo + (size_t)idx * 8)     = make_ushort4(lv[0], lv[1], lv[2], lv[3]);
        *(ushort4*)(out_lo + (size_t)idx * 8 + 4) = make_ushort4(lv[4], lv[5], lv[6], lv[7]);
    }
}

// ---------------------------------------------------------------------------
// K1: raw_alpha = softplus(silu(LN(h) @ W1 + b1) @ W2 + b2)   [B*T rows]
// 32 rows/block, 256 thr (4 waves). LN from global, bf16 hi/lo planes to LDS
// (row stride 2064B). MFMA: wave w = 32 rows x cols [w*32,w*32+32) (nt=2,
// rt=2), bf16x3. B frags coalesced from fragment-major W1f. Epilogue:
// silu*W2 partial per lane, shfl over lr, cross-wave add via LDS, softplus.
// ---------------------------------------------------------------------------
__global__ __launch_bounds__(256) void alpha_net_kernel(
    const float* __restrict__ h,
    const float* __restrict__ ln_g, const float* __restrict__ ln_b,
    const unsigned short* __restrict__ W1f_hi, const unsigned short* __restrict__ W1f_lo,
    const float* __restrict__ b1,
    const float* __restrict__ W2,   const float* __restrict__ b2,
    float* __restrict__ raw_alpha)
{
    __shared__ char planes[32 * 2064];     // per row: [hi 1024B][lo 1024B][pad 16B]
    __shared__ float part2[4][2][16];      // [wave][rt][row16]
    const int tid  = threadIdx.x;
    const int row0 = blockIdx.x * 32;
    const int wave = tid >> 6;
    const int lane = tid & 63;

    // ---- LN: wave handles 8 rows; lane covers cols c1..c1+3 and c2..c2+3 ----
    const int c1 = lane * 4;
    const int c2 = 256 + lane * 4;
    float4 g1 = *(const float4*)&ln_g[c1];
    float4 g2 = *(const float4*)&ln_g[c2];
    float4 o1 = *(const float4*)&ln_b[c1];
    float4 o2 = *(const float4*)&ln_b[c2];
    const int rbase8 = wave * 8;
    #pragma unroll
    for (int rr = 0; rr < 8; ++rr) {
        const float* hrow = h + (size_t)(row0 + rbase8 + rr) * D_DIM;
        float4 a  = *(const float4*)(hrow + c1);
        float4 bq = *(const float4*)(hrow + c2);
        float s  = a.x + a.y + a.z + a.w + bq.x + bq.y + bq.z + bq.w;
        float sq = a.x*a.x + a.y*a.y + a.z*a.z + a.w*a.w
                 + bq.x*bq.x + bq.y*bq.y + bq.z*bq.z + bq.w*bq.w;
        #pragma unroll
        for (int off = 32; off >= 1; off >>= 1) {
            s  += __shfl_xor(s,  off);
            sq += __shfl_xor(sq, off);
        }
        float mu  = s * (1.0f / 512.0f);
        float var = sq * (1.0f / 512.0f) - mu * mu;
        float inv = rsqrtf(var + 1e-5f);
        a.x  = (a.x  - mu) * inv * g1.x + o1.x;
        a.y  = (a.y  - mu) * inv * g1.y + o1.y;
        a.z  = (a.z  - mu) * inv * g1.z + o1.z;
        a.w  = (a.w  - mu) * inv * g1.w + o1.w;
        bq.x = (bq.x - mu) * inv * g2.x + o2.x;
        bq.y = (bq.y - mu) * inv * g2.y + o2.y;
        bq.z = (bq.z - mu) * inv * g2.z + o2.z;
        bq.w = (bq.w - mu) * inv * g2.w + o2.w;
        char* rb = planes + (rbase8 + rr) * 2064;
        ushort4 ha = make_ushort4(f2bf(a.x), f2bf(a.y), f2bf(a.z), f2bf(a.w));
        ushort4 hb = make_ushort4(f2bf(bq.x), f2bf(bq.y), f2bf(bq.z), f2bf(bq.w));
        ushort4 la = make_ushort4(f2bf(a.x - bf2f(ha.x)), f2bf(a.y - bf2f(ha.y)),
                                  f2bf(a.z - bf2f(ha.z)), f2bf(a.w - bf2f(ha.w)));
        ushort4 lb = make_ushort4(f2bf(bq.x - bf2f(hb.x)), f2bf(bq.y - bf2f(hb.y)),
                                  f2bf(bq.z - bf2f(hb.z)), f2bf(bq.w - bf2f(hb.w)));
        *(ushort4*)(rb + 2 * c1)        = ha;
        *(ushort4*)(rb + 2 * c2)        = hb;
        *(ushort4*)(rb + 1024 + 2 * c1) = la;
        *(ushort4*)(rb + 1024 + 2 * c2) = lb;
    }
    __syncthreads();

    // ---- MFMA: wave w -> 32 rows x cols [w*32, w*32+32) ----
    const int lr = lane & 15, lg = lane >> 4;
    const char* aBase0 = planes + lr * 2064;           // rows 0..15
    const char* aBase1 = planes + (16 + lr) * 2064;    // rows 16..31
    f32x4 acc[2][2];
    #pragma unroll
    for (int rt = 0; rt < 2; ++rt)
        #pragma unroll
        for (int nt = 0; nt < 2; ++nt) acc[rt][nt] = (f32x4){0.f, 0.f, 0.f, 0.f};
    for (int ks = 0; ks < 16; ++ks) {
        const int cofs = (4 * ks + lg) * 16;
        bf16x8 ahi0 = *(const bf16x8*)(aBase0 + cofs);
        bf16x8 alo0 = *(const bf16x8*)(aBase0 + 1024 + cofs);
        bf16x8 ahi1 = *(const bf16x8*)(aBase1 + cofs);
        bf16x8 alo1 = *(const bf16x8*)(aBase1 + 1024 + cofs);
        #pragma unroll
        for (int nt = 0; nt < 2; ++nt) {
            const size_t fo = ((size_t)((wave * 2 + nt) * 16 + ks) * 64 + lane) * 8;
            bf16x8 bhi = *(const bf16x8*)(W1f_hi + fo);
            bf16x8 blo = *(const bf16x8*)(W1f_lo + fo);
            acc[0][nt] = __builtin_amdgcn_mfma_f32_16x16x32_bf16(ahi0, bhi, acc[0][nt], 0, 0, 0);
            acc[0][nt] = __builtin_amdgcn_mfma_f32_16x16x32_bf16(ahi0, blo, acc[0][nt], 0, 0, 0);
            acc[0][nt] = __builtin_amdgcn_mfma_f32_16x16x32_bf16(alo0, bhi, acc[0][nt], 0, 0, 0);
            acc[1][nt] = __builtin_amdgcn_mfma_f32_16x16x32_bf16(ahi1, bhi, acc[1][nt], 0, 0, 0);
            acc[1][nt] = __builtin_amdgcn_mfma_f32_16x16x32_bf16(ahi1, blo, acc[1][nt], 0, 0, 0);
            acc[1][nt] = __builtin_amdgcn_mfma_f32_16x16x32_bf16(alo1, bhi, acc[1][nt], 0, 0, 0);
        }
    }

    // ---- epilogue: +b1, SiLU, *W2, reduce over this wave's 32 cols ----
    float p[2][4] = {};
    #pragma unroll
    for (int nt = 0; nt < 2; ++nt) {
        int n = (wave * 2 + nt) * 16 + lr;
        float b1v = b1[n], w2v = W2[n];
        #pragma unroll
        for (int rt = 0; rt < 2; ++rt)
            #pragma unroll
            for (int j = 0; j < 4; ++j) {
                float z = acc[rt][nt][j] + b1v;
                p[rt][j] += z / (1.f + expf(-z)) * w2v;
            }
    }
    #pragma unroll
    for (int rt = 0; rt < 2; ++rt)
        #pragma unroll
        for (int j = 0; j < 4; ++j) {
            p[rt][j] += __shfl_xor(p[rt][j], 1);
            p[rt][j] += __shfl_xor(p[rt][j], 2);
            p[rt][j] += __shfl_xor(p[rt][j], 4);
            p[rt][j] += __shfl_xor(p[rt][j], 8);
        }
    if (lr == 0) {
        #pragma unroll
        for (int rt = 0; rt < 2; ++rt)
            #pragma unroll
            for (int j = 0; j < 4; ++j) part2[wave][rt][lg * 4 + j] = p[rt][j];
    }
    __syncthreads();
    if (tid < 32) {
        int r16 = tid & 15, rt2 = tid >> 4;
        float z = part2[0][rt2][r16] + part2[1][rt2][r16]
                + part2[2][rt2][r16] + part2[3][rt2][r16] + b2[0];
        // jax softplus = max(z,0) + log1p(exp(-|z|))
        float sp = fmaxf(z, 0.f) + log1pf(expf(-fabsf(z)));
        raw_alpha[row0 + rt2 * 16 + r16] = sp;
    }
}

// ---------------------------------------------------------------------------
// K2a: masked chunk sums S[b][ch] over raw alpha. Grid (4, B), 256 thr.
// ---------------------------------------------------------------------------
__global__ __launch_bounds__(256) void chunk_sum_kernel(
    const float* __restrict__ raw, const int* __restrict__ ilen,
    float* __restrict__ S)
{
    __shared__ float wred[4];
    const int ch = blockIdx.x, b = blockIdx.y;
    const int tid = threadIdx.x;
    const int L = min(ilen[b], T_LEN);
    const int base = ch << 10;
    float local = 0.f;
    #pragma unroll
    for (int i = 0; i < 4; ++i) {
        int t = base + tid + (i << 8);
        if (t < L) local += raw[b * T_LEN + t];
    }
    #pragma unroll
    for (int off = 32; off >= 1; off >>= 1) local += __shfl_xor(local, off);
    if ((tid & 63) == 0) wred[tid >> 6] = local;
    __syncthreads();
    if (tid == 0) S[b * 4 + ch] = wred[0] + wred[1] + wred[2] + wred[3];
}

// ---------------------------------------------------------------------------
// K2b: per (b, chunk): scale raw -> alpha, inclusive scan -> c. Grid (4, B),
// 1024 thr (16 waves). Carry derived from chunk sums (algebraically exact).
// ---------------------------------------------------------------------------
__global__ __launch_bounds__(1024) void scan_chunk_kernel(
    const float* __restrict__ raw, const float* __restrict__ S,
    const int* __restrict__ tgt, const int* __restrict__ ilen,
    float* __restrict__ alpha_out, float* __restrict__ c_out)
{
    __shared__ float wsum_lds[16];
    __shared__ float wscan_lds[16];
    const int ch = blockIdx.x, b = blockIdx.y;
    const int tid  = threadIdx.x;
    const int wid  = tid >> 6;
    const int lane = tid & 63;
    const int L    = min(ilen[b], T_LEN);
    const float Nf = (float)tgt[b];

    float s0 = S[b * 4 + 0], s1 = S[b * 4 + 1], s2 = S[b * 4 + 2], s3 = S[b * 4 + 3];
    float sums  = s0 + s1 + s2 + s3;
    float scale = Nf / (sums + EPSF);
    float uu    = (sums < 10.f * EPSF) ? 1.f : 0.f;
    float unif  = Nf / fmaxf((float)L, 1.f);
    float prefix = (ch > 0 ? s0 : 0.f) + (ch > 1 ? s1 : 0.f) + (ch > 2 ? s2 : 0.f);
    float carry  = (1.f - uu) * scale * prefix
                 + uu * unif * (float)min(L, ch << 10);

    int t = (ch << 10) + tid;
    float m = (t < L) ? 1.f : 0.f;
    float a = (raw[b * T_LEN + t] * m * scale) * (1.f - uu) + m * unif * uu;
    alpha_out[b * T_LEN + t] = a;

    float v = a;
    #pragma unroll
    for (int off = 1; off < 64; off <<= 1) {
        float tv = __shfl_up(v, off);
        if (lane >= off) v += tv;
    }
    if (lane == 63) wsum_lds[wid] = v;
    __syncthreads();
    if (wid == 0 && lane < 16) {
        float s = wsum_lds[lane];
        #pragma unroll
        for (int off = 1; off < 16; off <<= 1) {
            float tv = __shfl_up(s, off);
            if (lane >= off) s += tv;
        }
        wscan_lds[lane] = s;
    }
    __syncthreads();
    float woff = (wid > 0) ? wscan_lds[wid - 1] : 0.f;
    c_out[b * T_LEN + t] = carry + woff + v;
}

// ---------------------------------------------------------------------------
// K3: per (b, bin n): binary-search contiguous frame range, accumulate
// hw[b,n,:] = sum_t w*h[b,t,:] (written as bf16 for K4's MFMA A operand),
// plus cif_mass / frame_durations / token_mask.
// ---------------------------------------------------------------------------
__global__ __launch_bounds__(256) void cif_gather_kernel(
    const float* __restrict__ h, const float* __restrict__ alpha,
    const float* __restrict__ c_arr,
    const int* __restrict__ tgt, const int* __restrict__ ilen,
    unsigned short* __restrict__ hwb, float* __restrict__ fd_out,
    float* __restrict__ cm_out, float* __restrict__ tm_out)
{
    __shared__ float part[514];        // 512 col partials + wsum,fdsum
    const int n   = blockIdx.x;
    const int b   = blockIdx.y;
    const int tid = threadIdx.x;
    const int oidx = b * N_MAX + n;
    if (n >= tgt[b]) {
        if (tid == 0) { fd_out[oidx] = 0.f; cm_out[oidx] = 0.f; tm_out[oidx] = 0.f; }
        return;   // hwb row left as (finite bf16) poison; K4 masks it to zero
    }
    const int L = min(ilen[b], T_LEN);
    const float* cb = c_arr + b * T_LEN;
    const float* ab = alpha + b * T_LEN;
    const float nf  = (float)n;
    const float nf1 = nf + 1.0f;

    // first t with c[t] > n
    int lo = 0, hi = T_LEN;
    while (lo < hi) { int mid = (lo + hi) >> 1; if (cb[mid] > nf) hi = mid; else lo = mid + 1; }
    const int t0 = lo;
    // first t with c[t] >= n+1  (== last contributing frame, since c_prev[t]=c[t-1])
    lo = 0; hi = T_LEN;
    while (lo < hi) { int mid = (lo + hi) >> 1; if (cb[mid] >= nf1) hi = mid; else lo = mid + 1; }
    int t1 = min(lo, L - 1);

    const int par = tid >> 7;          // 0: even frames, 1: odd frames
    const int c4  = (tid & 127) << 2;  // float column base
    float4 acc = make_float4(0.f, 0.f, 0.f, 0.f);
    float wsum = 0.f, fdsum = 0.f;
    const float* hb = h + (size_t)(b * T_LEN) * D_DIM;
    for (int t = t0 + par; t <= t1; t += 2) {
        float a = ab[t], c = cb[t];
        float cp = c - a;                               // c_prev, same arithmetic as ref
        float w  = fmaxf(fminf(c, nf1) - fmaxf(cp, nf), 0.f);
        wsum  += w;
        fdsum += w / (a + EPSF);
        const float4 hv = *(const float4*)(hb + (size_t)t * D_DIM + c4);
        acc.x += w * hv.x;
        acc.y += w * hv.y;
        acc.z += w * hv.z;
        acc.w += w * hv.w;
    }
    if (par == 1) {
        *(float4*)&part[c4] = acc;
        if (tid == 128) { part[512] = wsum; part[513] = fdsum; }
    }
    __syncthreads();
    if (par == 0) {
        float4 p = *(const float4*)&part[c4];
        acc.x += p.x; acc.y += p.y; acc.z += p.z; acc.w += p.w;
        *(ushort4*)(hwb + (size_t)oidx * D_DIM + c4) =
            make_ushort4(f2bf(acc.x), f2bf(acc.y), f2bf(acc.z), f2bf(acc.w));
        if (tid == 0) {
            fd_out[oidx] = fdsum + part[513];
            cm_out[oidx] = wsum + part[512];
            tm_out[oidx] = 1.f;
        }
    }
}

// ---------------------------------------------------------------------------
// K4: tokens = (hw @ Wv + cif_mass*bv) * token_mask.  M=6400, N=512, K=512.
// Plain bf16 MFMA; B frags coalesced from fragment-major Wvf. Grid (100, 4);
// wave -> 16 rows x 8 n-tiles.
// ---------------------------------------------------------------------------
__global__ __launch_bounds__(256) void token_gemm_kernel(
    const unsigned short* __restrict__ hwb, const unsigned short* __restrict__ Wvf,
    const float* __restrict__ bv, const float* __restrict__ cm,
    const int* __restrict__ tgt, float* __restrict__ tokens)
{
    const int tid  = threadIdx.x;
    const int wave = tid >> 6;
    const int lane = tid & 63;
    const int lr = lane & 15, lg = lane >> 4;
    const int arow = blockIdx.x * 64 + wave * 16 + lr;
    const int colb = blockIdx.y * 128;

    f32x4 acc[8];
    #pragma unroll
    for (int nt = 0; nt < 8; ++nt) acc[nt] = (f32x4){0.f, 0.f, 0.f, 0.f};
    for (int ks = 0; ks < 16; ++ks) {
        const int kofs = ks * 32 + lg * 8;
        bf16x8 a = *(const bf16x8*)(hwb + (size_t)arow * D_DIM + kofs);
        #pragma unroll
        for (int nt = 0; nt < 8; ++nt) {
            const int ntg = blockIdx.y * 8 + nt;
            bf16x8 bq = *(const bf16x8*)(Wvf + ((size_t)(ntg * 16 + ks) * 64 + lane) * 8);
            acc[nt] = __builtin_amdgcn_mfma_f32_16x16x32_bf16(a, bq, acc[nt], 0, 0, 0);
        }
    }

    // epilogue: lane owns rows (lg*4+j) of its wave's 16-row tile, col lr per tile
    float cmr[4], mr[4];
    int   rr[4];
    #pragma unroll
    for (int j = 0; j < 4; ++j) {
        int r = blockIdx.x * 64 + wave * 16 + lg * 4 + j;
        int bb = r / N_MAX;
        int nn = r - bb * N_MAX;
        rr[j] = r;
        mr[j] = (nn < tgt[bb]) ? 1.f : 0.f;
        cmr[j] = cm[r];
    }
    #pragma unroll
    for (int nt = 0; nt < 8; ++nt) {
        int col = colb + nt * 16 + lr;
        float bvv = bv[col];
        #pragma unroll
        for (int j = 0; j < 4; ++j)
            tokens[(size_t)rr[j] * D_DIM + col] = mr[j] * (acc[nt][j] + cmr[j] * bvv);
    }
}

// ---------------------------------------------------------------------------
extern "C" void kernel_launch(void* const* d_in, const int* in_sizes, int n_in,
                              void* d_out, int out_size, void* d_ws, size_t ws_size,
                              hipStream_t stream)
{
    (void)in_sizes; (void)n_in; (void)out_size; (void)ws_size;
    const float* h    = (const float*)d_in[0];
    const int*   tgt  = (const int*)  d_in[1];
    const int*   ilen = (const int*)  d_in[2];
    const float* lng  = (const float*)d_in[3];
    const float* lnb  = (const float*)d_in[4];
    const float* W1   = (const float*)d_in[5];
    const float* b1   = (const float*)d_in[6];
    const float* W2   = (const float*)d_in[7];
    const float* b2   = (const float*)d_in[8];
    const float* Wv   = (const float*)d_in[9];
    const float* bv   = (const float*)d_in[10];

    float* out    = (float*)d_out;
    float* tokens = out;                                        // [B, N_MAX, V]
    float* fd     = tokens + (size_t)B_SZ * N_MAX * D_DIM;      // [B, N_MAX]
    float* cm     = fd + B_SZ * N_MAX;                          // [B, N_MAX]
    float* tm     = cm + B_SZ * N_MAX;                          // [B, N_MAX]
    float* alpha  = tm + B_SZ * N_MAX;                          // [B, T]
    float* raw    = alpha + B_SZ * T_LEN;                       // [B, T]

    float* c_ws = (float*)d_ws;                                 // [B, T]
    unsigned short* hwb    = (unsigned short*)(c_ws + B_SZ * T_LEN);   // [B*N_MAX, D] bf16
    unsigned short* W1f_hi = hwb + (size_t)B_SZ * N_MAX * D_DIM;       // [HID*D] frag-major
    unsigned short* W1f_lo = W1f_hi + (size_t)HID * D_DIM;
    unsigned short* Wvf    = W1f_lo + (size_t)HID * D_DIM;             // [D*D] frag-major
    float* S = (float*)(Wvf + (size_t)D_DIM * D_DIM);                  // [B, 4] chunk sums

    // W1: (128/16)*(512/32)*64 = 8192 frags -> 32 blocks; Wv: 32768 -> 128 blocks
    frag_pack_kernel<<<32, 256, 0, stream>>>(W1, W1f_hi, W1f_lo, D_DIM, HID);
    frag_pack_kernel<<<128, 256, 0, stream>>>(Wv, Wvf, (unsigned short*)nullptr, D_DIM, D_DIM);
    alpha_net_kernel<<<(B_SZ * T_LEN) / 32, 256, 0, stream>>>(h, lng, lnb, W1f_hi, W1f_lo,
                                                              b1, W2, b2, raw);
    chunk_sum_kernel<<<dim3(4, B_SZ), 256, 0, stream>>>(raw, ilen, S);
    scan_chunk_kernel<<<dim3(4, B_SZ), 1024, 0, stream>>>(raw, S, tgt, ilen, alpha, c_ws);
    cif_gather_kernel<<<dim3(N_MAX, B_SZ), 256, 0, stream>>>(h, alpha, c_ws, tgt, ilen,
                                                             hwb, fd, cm, tm);
    token_gemm_kernel<<<dim3(100, 4), 256, 0, stream>>>(hwb, Wvf, bv, cm, tgt, tokens);
}